// Round 8
// baseline (115.571 us; speedup 1.0000x reference)
//
#include <hip/hip_runtime.h>
#include <hip/hip_bf16.h>
#include <hip/hip_fp8.h>
#include <math.h>

#define D_DIM 128
#define SIM_THR 0.2f
#define DEG_THR 3.0f
#define PT_THR 0.1
#define EPS_CS 1e-8
#define NODE_MARGIN 0.022f   // 6.3 sigma of fp8 csim error (worst: deg==1)
#define PRUNE_MARGIN 0.022f  // 6.1 sigma of fp8 e_arr error
#define PK 4294967296.0      // 2^32: deg-count scale inside packed f64 atomic

typedef unsigned short u16;
typedef unsigned int u32;

// ---------------- primary ws layout (bytes) ----------------
// 0        cd      double[N]  800000  (zeroed by node_pre; packed deg*2^32+c)
// 800000   na      double[N]  800000
// 1600000  nx      f32[N]     400000
// 2000000  r_s     f32[N]     400000
// 2400000  r_d     f32[N]     400000
// 2800000  r_o     f32[N]     400000
// 3200000  e_arr   bf16[E]    1280000
// 4480000  pack    f32[8N]    3200000  {r_s,r_d,r_o,|x|, as,ad,ao,inv_na}
// 7680000  cfix    f32[N]     400000   (zeroed lazily per flagged node)
// 8080000  bitmap  u32[3200]  12800    (zeroed by node_pre)
// 8092800  flags   int[4]
// 8092816  G       f32[9]
#define WS_NEED 8092900

__device__ __forceinline__ float bf2f(u16 u) {
    return __uint_as_float(((u32)u) << 16);
}
__device__ __forceinline__ float f8f(u32 v) {
    __hip_fp8_e4m3 t;
    t.__x = (__hip_fp8_storage_t)v;
    return (float)t;
}
__device__ __forceinline__ u16 f2bf(float f) {
    __hip_bfloat16 b = __float2bfloat16(f);
    return *(u16*)&b;
}

// ---- K1: per node: x8 fp8 row, |x|, r_k = dot(x,p_k); zero cd+bitmap;
//      block 0 wave 0 computes prompt flags + 3x3 Gram ----
__global__ void node_pre_fp8(const float* __restrict__ x,
                             const float* __restrict__ ps,
                             const float* __restrict__ pd,
                             const float* __restrict__ po,
                             u32* __restrict__ x8d,
                             float* __restrict__ nx,
                             float* __restrict__ rs,
                             float* __restrict__ rd,
                             float* __restrict__ ro,
                             double* __restrict__ cd,
                             u32* __restrict__ bitmap, int nbmw,
                             int* __restrict__ flags,
                             float* __restrict__ G, int N) {
    int g = threadIdx.x >> 5;
    int lane = threadIdx.x & 31;
    int n = blockIdx.x * 8 + g;
    int gid = blockIdx.x * 256 + threadIdx.x;
    if (gid < nbmw) bitmap[gid] = 0u;
    if (n < N) {
        int off = lane * 4;
        const float4 v = *(const float4*)(x + (size_t)n * D_DIM + off);
        const float4 s = *(const float4*)(ps + off);
        const float4 d = *(const float4*)(pd + off);
        const float4 o = *(const float4*)(po + off);
        float sq = v.x * v.x + v.y * v.y + v.z * v.z + v.w * v.w;
        float drs = v.x * s.x + v.y * s.y + v.z * s.z + v.w * s.w;
        float drd = v.x * d.x + v.y * d.y + v.z * d.z + v.w * d.w;
        float dro = v.x * o.x + v.y * o.y + v.z * o.z + v.w * o.w;
        for (int m = 16; m; m >>= 1) {
            sq += __shfl_xor(sq, m, 32);
            drs += __shfl_xor(drs, m, 32);
            drd += __shfl_xor(drd, m, 32);
            dro += __shfl_xor(dro, m, 32);
        }
        float nrm = sqrtf(sq);
        float inv = 1.0f / nrm;
        __hip_fp8_e4m3 q0(v.x * inv), q1(v.y * inv), q2(v.z * inv), q3(v.w * inv);
        u32 packed = (u32)q0.__x | ((u32)q1.__x << 8) |
                     ((u32)q2.__x << 16) | ((u32)q3.__x << 24);
        x8d[(size_t)n * 32 + lane] = packed;
        if (lane == 0) {
            nx[n] = nrm;
            rs[n] = drs;
            rd[n] = drd;
            ro[n] = dro;
            cd[n] = 0.0;
        }
    }
    if (blockIdx.x == 0 && threadIdx.x < 64) {
        int t = threadIdx.x;
        float s0 = ps[t], s1 = ps[t + 64];
        float d0 = pd[t], d1 = pd[t + 64];
        float o0 = po[t], o1 = po[t + 64];
        float ss = s0 * s0 + s1 * s1;
        float sd = s0 * d0 + s1 * d1;
        float so = s0 * o0 + s1 * o1;
        float dd = d0 * d0 + d1 * d1;
        float dO = d0 * o0 + d1 * o1;
        float oo = o0 * o0 + o1 * o1;
        for (int m = 32; m; m >>= 1) {
            ss += __shfl_xor(ss, m);
            sd += __shfl_xor(sd, m);
            so += __shfl_xor(so, m);
            dd += __shfl_xor(dd, m);
            dO += __shfl_xor(dO, m);
            oo += __shfl_xor(oo, m);
        }
        unsigned long long zs = __ballot(s0 == 0.0f || s1 == 0.0f);
        unsigned long long zd = __ballot(d0 == 0.0f || d1 == 0.0f);
        unsigned long long zo = __ballot(o0 == 0.0f || o1 == 0.0f);
        if (t == 0) {
            flags[0] = (zs == 0ull);
            flags[1] = (zd == 0ull);
            flags[2] = (zo == 0ull);
            G[0] = ss; G[1] = sd; G[2] = so;
            G[3] = sd; G[4] = dd; G[5] = dO;
            G[6] = so; G[7] = dO; G[8] = oo;
        }
    }
}

// ---- K2: fp8 edge sim, 4 edges per 32-lane group; packed f64 atomic ----
__global__ void edge_sim_fp8(const u32* __restrict__ x8d,
                             const int* __restrict__ ei,
                             double* __restrict__ cd,
                             u16* __restrict__ e_arr,
                             int E) {
    int lane = threadIdx.x & 31;
    int grp = blockIdx.x * 8 + (threadIdx.x >> 5);
    int base = grp * 4;
    if (base >= E) return;

    int r[4], c4[4];
    #pragma unroll
    for (int k = 0; k < 4; ++k) {
        int e = base + k;
        int src = (e < E) ? e : base;
        r[k] = ei[src];
        c4[k] = ei[E + src];
    }
    u32 a[4], b[4];
    #pragma unroll
    for (int k = 0; k < 4; ++k) {
        a[k] = x8d[(size_t)r[k] * 32 + lane];
        b[k] = x8d[(size_t)c4[k] * 32 + lane];
    }
    float d[4];
    #pragma unroll
    for (int k = 0; k < 4; ++k) {
        d[k] = f8f(a[k] & 255u) * f8f(b[k] & 255u) +
               f8f((a[k] >> 8) & 255u) * f8f((b[k] >> 8) & 255u) +
               f8f((a[k] >> 16) & 255u) * f8f((b[k] >> 16) & 255u) +
               f8f(a[k] >> 24) * f8f(b[k] >> 24);
    }
    for (int m = 16; m; m >>= 1) {
        #pragma unroll
        for (int k = 0; k < 4; ++k) d[k] += __shfl_xor(d[k], m, 32);
    }
    if (lane < 4) {
        int e = base + lane;
        if (e < E) {
            float dv = (lane == 0) ? d[0] : (lane == 1) ? d[1]
                     : (lane == 2) ? d[2] : d[3];
            e_arr[e] = f2bf(dv);
            atomicAdd(&cd[c4[lane]], (double)dv + PK);
        }
    }
}

// ---- K3: masks -> x_new; na; pack; flag borderline-csim nodes ----
__global__ void node_prompt_kernel(const float* __restrict__ x,
                                   const double* __restrict__ cd,
                                   const float* __restrict__ ps,
                                   const float* __restrict__ pd,
                                   const float* __restrict__ po,
                                   const int* __restrict__ flags,
                                   const float* __restrict__ nx,
                                   const float* __restrict__ rs,
                                   const float* __restrict__ rd,
                                   const float* __restrict__ ro,
                                   float* __restrict__ xn,
                                   double* __restrict__ na,
                                   float* __restrict__ pack,
                                   u32* __restrict__ bitmap,
                                   float* __restrict__ cfix, int N) {
    int g = threadIdx.x >> 5;
    int lane = threadIdx.x & 31;
    int n = blockIdx.x * 8 + g;
    if (n >= N) return;
    double v = cd[n];
    double degd = floor(v * (1.0 / PK) + 0.5);
    float dg = (float)degd;
    float cc = (float)(v - degd * PK);
    float csim = (dg > 0.0f) ? (cc / fmaxf(dg, 1.0f)) : INFINITY;
    bool ms = (csim <= SIM_THR);
    bool md = (dg <= DEG_THR);
    bool mo = !(ms || md);
    int plen = (ms && flags[0]) + (md && flags[1]) + (mo && flags[2]);
    float invp = (plen > 0) ? (1.0f / (float)plen) : 0.0f;

    int off = lane * 4;
    const float4 xv = *(const float4*)(x + (size_t)n * D_DIM + off);
    const float4 s  = *(const float4*)(ps + off);
    const float4 dd = *(const float4*)(pd + off);
    const float4 o  = *(const float4*)(po + off);

    float4 f;
    f.x = (ms ? s.x : 0.0f) + (md ? dd.x : 0.0f) + (mo ? o.x : 0.0f);
    f.y = (ms ? s.y : 0.0f) + (md ? dd.y : 0.0f) + (mo ? o.y : 0.0f);
    f.z = (ms ? s.z : 0.0f) + (md ? dd.z : 0.0f) + (mo ? o.z : 0.0f);
    f.w = (ms ? s.w : 0.0f) + (md ? dd.w : 0.0f) + (mo ? o.w : 0.0f);

    float4 r;
    r.x = xv.x + f.x * invp;
    r.y = xv.y + f.y * invp;
    r.z = xv.z + f.z * invp;
    r.w = xv.w + f.w * invp;

    *(float4*)(xn + (size_t)n * D_DIM + off) = r;

    double sq = (double)r.x * r.x + (double)r.y * r.y + (double)r.z * r.z + (double)r.w * r.w;
    for (int m = 16; m; m >>= 1) sq += __shfl_xor(sq, m, 32);
    if (lane == 0) {
        double nrm = sqrt(sq);
        double nad = (nrm > EPS_CS) ? nrm : EPS_CS;
        na[n] = nad;
        float as = ms ? invp : 0.0f;
        float ad = md ? invp : 0.0f;
        float ao = mo ? invp : 0.0f;
        *(float4*)(pack + (size_t)n * 8)     = make_float4(rs[n], rd[n], ro[n], nx[n]);
        *(float4*)(pack + (size_t)n * 8 + 4) = make_float4(as, ad, ao, (float)(1.0 / nad));
        if (dg > 0.0f && fabsf(csim - SIM_THR) < NODE_MARGIN) {
            cfix[n] = 0.0f;
            atomicOr(&bitmap[n >> 5], 1u << (n & 31));
        }
    }
}

// ---- K4: rescan edges; recompute e exactly (f32 x, f64 dot) for edges
//      targeting flagged nodes; accumulate into cfix ----
__global__ void edge_fix_scan(const float* __restrict__ x,
                              const int* __restrict__ ei,
                              const float* __restrict__ nx,
                              const u32* __restrict__ bitmap,
                              float* __restrict__ cfix, int E) {
    int e = blockIdx.x * 256 + threadIdx.x;
    if (e >= E) return;
    int col = ei[E + e];
    if (!((bitmap[col >> 5] >> (col & 31)) & 1u)) return;
    int row = ei[e];
    const float4* xr = (const float4*)(x + (size_t)row * D_DIM);
    const float4* xc = (const float4*)(x + (size_t)col * D_DIM);
    double s = 0.0;
    for (int i = 0; i < 32; ++i) {
        float4 a = xr[i], b = xc[i];
        s += (double)a.x * b.x + (double)a.y * b.y +
             (double)a.z * b.z + (double)a.w * b.w;
    }
    float ev = (float)(s / ((double)nx[row] * (double)nx[col]));
    atomicAdd(&cfix[col], ev);
}

// ---- K5: rewrite xn/na/pack for flagged nodes using exact csim ----
__global__ void node_fix_kernel(const float* __restrict__ x,
                                const double* __restrict__ cd,
                                const float* __restrict__ cfix,
                                const u32* __restrict__ bitmap,
                                const float* __restrict__ ps,
                                const float* __restrict__ pd,
                                const float* __restrict__ po,
                                const int* __restrict__ flags,
                                const float* __restrict__ nx,
                                const float* __restrict__ rs,
                                const float* __restrict__ rd,
                                const float* __restrict__ ro,
                                float* __restrict__ xn,
                                double* __restrict__ na,
                                float* __restrict__ pack, int N) {
    int g = threadIdx.x >> 5;
    int lane = threadIdx.x & 31;
    int n = blockIdx.x * 8 + g;
    if (n >= N) return;
    if (!((bitmap[n >> 5] >> (n & 31)) & 1u)) return;

    double v = cd[n];
    double degd = floor(v * (1.0 / PK) + 0.5);
    float dg = (float)degd;                 // flagged => dg > 0
    float csim = cfix[n] / fmaxf(dg, 1.0f);
    bool ms = (csim <= SIM_THR);
    bool md = (dg <= DEG_THR);
    bool mo = !(ms || md);
    int plen = (ms && flags[0]) + (md && flags[1]) + (mo && flags[2]);
    float invp = (plen > 0) ? (1.0f / (float)plen) : 0.0f;

    int off = lane * 4;
    const float4 xv = *(const float4*)(x + (size_t)n * D_DIM + off);
    const float4 s  = *(const float4*)(ps + off);
    const float4 dd = *(const float4*)(pd + off);
    const float4 o  = *(const float4*)(po + off);

    float4 f;
    f.x = (ms ? s.x : 0.0f) + (md ? dd.x : 0.0f) + (mo ? o.x : 0.0f);
    f.y = (ms ? s.y : 0.0f) + (md ? dd.y : 0.0f) + (mo ? o.y : 0.0f);
    f.z = (ms ? s.z : 0.0f) + (md ? dd.z : 0.0f) + (mo ? o.z : 0.0f);
    f.w = (ms ? s.w : 0.0f) + (md ? dd.w : 0.0f) + (mo ? o.w : 0.0f);

    float4 r;
    r.x = xv.x + f.x * invp;
    r.y = xv.y + f.y * invp;
    r.z = xv.z + f.z * invp;
    r.w = xv.w + f.w * invp;

    *(float4*)(xn + (size_t)n * D_DIM + off) = r;

    double sq = (double)r.x * r.x + (double)r.y * r.y + (double)r.z * r.z + (double)r.w * r.w;
    for (int m = 16; m; m >>= 1) sq += __shfl_xor(sq, m, 32);
    if (lane == 0) {
        double nrm = sqrt(sq);
        double nad = (nrm > EPS_CS) ? nrm : EPS_CS;
        na[n] = nad;
        float as = ms ? invp : 0.0f;
        float ad = md ? invp : 0.0f;
        float ao = mo ? invp : 0.0f;
        *(float4*)(pack + (size_t)n * 8)     = make_float4(rs[n], rd[n], ro[n], nx[n]);
        *(float4*)(pack + (size_t)n * 8 + 4) = make_float4(as, ad, ao, (float)(1.0 / nad));
    }
}

// ---- K6: fused factored prune + in-block exact fixup (overflow-safe) ----
__global__ void edge_prune_fused(const int* __restrict__ ei,
                                 const u16* __restrict__ e_arr,
                                 const float* __restrict__ pack,
                                 const float* __restrict__ G,
                                 const float* __restrict__ xn,
                                 const double* __restrict__ na,
                                 float* __restrict__ keep, int E) {
    __shared__ int s_list[256];
    __shared__ int s_cnt;
    int tid = threadIdx.x;
    if (tid == 0) s_cnt = 0;
    __syncthreads();

    int e = blockIdx.x * 256 + tid;
    if (e < E) {
        int i = ei[e], j = ei[E + e];
        const float4 ri = *(const float4*)(pack + (size_t)i * 8);
        const float4 ai = *(const float4*)(pack + (size_t)i * 8 + 4);
        const float4 rj = *(const float4*)(pack + (size_t)j * 8);
        const float4 aj = *(const float4*)(pack + (size_t)j * 8 + 4);
        float ev = bf2f(e_arr[e]);
        float dot = ev * ri.w * rj.w
                  + aj.x * ri.x + aj.y * ri.y + aj.z * ri.z
                  + ai.x * rj.x + ai.y * rj.y + ai.z * rj.z;
        dot += ai.x * (G[0] * aj.x + G[1] * aj.y + G[2] * aj.z)
             + ai.y * (G[3] * aj.x + G[4] * aj.y + G[5] * aj.z)
             + ai.z * (G[6] * aj.x + G[7] * aj.y + G[8] * aj.z);
        float cosv = dot * ai.w * aj.w;
        keep[e] = (cosv >= 0.1f) ? 1.0f : 0.0f;
        if (fabsf(cosv - 0.1f) < PRUNE_MARGIN) {
            int idx = atomicAdd(&s_cnt, 1);
            if (idx < 256) {
                s_list[idx] = e;
            } else {
                // overflow: self-service exact recompute (rare)
                const float4* xr = (const float4*)(xn + (size_t)i * D_DIM);
                const float4* xc = (const float4*)(xn + (size_t)j * D_DIM);
                double sd = 0.0;
                for (int it = 0; it < 32; ++it) {
                    float4 a = xr[it], b = xc[it];
                    sd += (double)a.x * b.x + (double)a.y * b.y +
                          (double)a.z * b.z + (double)a.w * b.w;
                }
                double cs = sd / (na[i] * na[j]);
                keep[e] = (cs >= PT_THR) ? 1.0f : 0.0f;
            }
        }
    }
    __syncthreads();

    int cnt = s_cnt < 256 ? s_cnt : 256;
    int lane = tid & 31;
    int grp = tid >> 5;
    for (int it = grp; it < cnt; it += 8) {
        int ee = s_list[it];
        int row = ei[ee], col = ei[E + ee];
        const float4 a = *(const float4*)(xn + (size_t)row * D_DIM + lane * 4);
        const float4 b = *(const float4*)(xn + (size_t)col * D_DIM + lane * 4);
        double d = (double)a.x * b.x + (double)a.y * b.y +
                   (double)a.z * b.z + (double)a.w * b.w;
        for (int m = 16; m; m >>= 1) d += __shfl_xor(d, m, 32);
        if (lane == 0) {
            double cs = d / (na[row] * na[col]);
            keep[ee] = (cs >= PT_THR) ? 1.0f : 0.0f;
        }
    }
}

// ================= fallback path (small ws): bf16 pipeline, exact prune ====
__global__ void node_pre_bf16(const float* __restrict__ x,
                              const float* __restrict__ ps,
                              const float* __restrict__ pd,
                              const float* __restrict__ po,
                              u16* __restrict__ xnorm,
                              double* __restrict__ cd,
                              int* __restrict__ flags, int N) {
    int g = threadIdx.x >> 5;
    int lane = threadIdx.x & 31;
    int n = blockIdx.x * 8 + g;
    if (n < N) {
        int off = lane * 4;
        const float4 v = *(const float4*)(x + (size_t)n * D_DIM + off);
        float sq = v.x * v.x + v.y * v.y + v.z * v.z + v.w * v.w;
        for (int m = 16; m; m >>= 1) sq += __shfl_xor(sq, m, 32);
        float inv = 1.0f / sqrtf(sq);
        *(ushort4*)(xnorm + (size_t)n * D_DIM + off) =
            make_ushort4(f2bf(v.x * inv), f2bf(v.y * inv), f2bf(v.z * inv), f2bf(v.w * inv));
        if (lane == 0) cd[n] = 0.0;
    }
    if (blockIdx.x == 0 && threadIdx.x < 64) {
        int t = threadIdx.x;
        unsigned long long zs = __ballot(ps[t] == 0.0f || ps[t + 64] == 0.0f);
        unsigned long long zd = __ballot(pd[t] == 0.0f || pd[t + 64] == 0.0f);
        unsigned long long zo = __ballot(po[t] == 0.0f || po[t + 64] == 0.0f);
        if (t == 0) {
            flags[0] = (zs == 0ull);
            flags[1] = (zd == 0ull);
            flags[2] = (zo == 0ull);
        }
    }
}

__global__ void edge_sim_bf16(const u16* __restrict__ xnorm,
                              const int* __restrict__ ei,
                              double* __restrict__ cd, int E) {
    int lane = threadIdx.x & 31;
    int grp = blockIdx.x * 8 + (threadIdx.x >> 5);
    int base = grp * 4;
    if (base >= E) return;
    int r[4], c4[4];
    #pragma unroll
    for (int k = 0; k < 4; ++k) {
        int e = base + k;
        int src = (e < E) ? e : base;
        r[k] = ei[src];
        c4[k] = ei[E + src];
    }
    float d[4];
    #pragma unroll
    for (int k = 0; k < 4; ++k) {
        ushort4 a = *(const ushort4*)(xnorm + (size_t)r[k] * D_DIM + lane * 4);
        ushort4 b = *(const ushort4*)(xnorm + (size_t)c4[k] * D_DIM + lane * 4);
        d[k] = bf2f(a.x) * bf2f(b.x) + bf2f(a.y) * bf2f(b.y) +
               bf2f(a.z) * bf2f(b.z) + bf2f(a.w) * bf2f(b.w);
    }
    for (int m = 16; m; m >>= 1) {
        #pragma unroll
        for (int k = 0; k < 4; ++k) d[k] += __shfl_xor(d[k], m, 32);
    }
    if (lane < 4) {
        int e = base + lane;
        if (e < E) {
            float dv = (lane == 0) ? d[0] : (lane == 1) ? d[1]
                     : (lane == 2) ? d[2] : d[3];
            atomicAdd(&cd[c4[lane]], (double)dv + PK);
        }
    }
}

__global__ void node_prompt_fb(const float* __restrict__ x,
                               const double* __restrict__ cd,
                               const float* __restrict__ ps,
                               const float* __restrict__ pd,
                               const float* __restrict__ po,
                               const int* __restrict__ flags,
                               float* __restrict__ xn,
                               double* __restrict__ na, int N) {
    int g = threadIdx.x >> 5;
    int lane = threadIdx.x & 31;
    int n = blockIdx.x * 8 + g;
    if (n >= N) return;
    double v = cd[n];
    double degd = floor(v * (1.0 / PK) + 0.5);
    float dg = (float)degd;
    float cc = (float)(v - degd * PK);
    float csim = (dg > 0.0f) ? (cc / fmaxf(dg, 1.0f)) : INFINITY;
    bool ms = (csim <= SIM_THR);
    bool md = (dg <= DEG_THR);
    bool mo = !(ms || md);
    int plen = (ms && flags[0]) + (md && flags[1]) + (mo && flags[2]);
    float invp = (plen > 0) ? (1.0f / (float)plen) : 0.0f;
    int off = lane * 4;
    const float4 xv = *(const float4*)(x + (size_t)n * D_DIM + off);
    const float4 s  = *(const float4*)(ps + off);
    const float4 dd = *(const float4*)(pd + off);
    const float4 o  = *(const float4*)(po + off);
    float4 r;
    r.x = xv.x + ((ms ? s.x : 0.0f) + (md ? dd.x : 0.0f) + (mo ? o.x : 0.0f)) * invp;
    r.y = xv.y + ((ms ? s.y : 0.0f) + (md ? dd.y : 0.0f) + (mo ? o.y : 0.0f)) * invp;
    r.z = xv.z + ((ms ? s.z : 0.0f) + (md ? dd.z : 0.0f) + (mo ? o.z : 0.0f)) * invp;
    r.w = xv.w + ((ms ? s.w : 0.0f) + (md ? dd.w : 0.0f) + (mo ? o.w : 0.0f)) * invp;
    *(float4*)(xn + (size_t)n * D_DIM + off) = r;
    double sq = (double)r.x * r.x + (double)r.y * r.y + (double)r.z * r.z + (double)r.w * r.w;
    for (int m = 16; m; m >>= 1) sq += __shfl_xor(sq, m, 32);
    if (lane == 0) {
        double nrm = sqrt(sq);
        na[n] = (nrm > EPS_CS) ? nrm : EPS_CS;
    }
}

__global__ void edge_prune_exact(const float* __restrict__ xn,
                                 const int* __restrict__ ei,
                                 const double* __restrict__ na,
                                 float* __restrict__ keep, int E) {
    int lane = threadIdx.x & 31;
    int grp = blockIdx.x * 8 + (threadIdx.x >> 5);
    int e0 = grp * 2, e1 = e0 + 1;
    if (e0 >= E) return;
    bool has1 = (e1 < E);
    int row0 = ei[e0], col0 = ei[E + e0];
    int row1 = has1 ? ei[e1] : row0;
    int col1 = has1 ? ei[E + e1] : col0;
    const float4 a0 = *(const float4*)(xn + (size_t)row0 * D_DIM + lane * 4);
    const float4 b0 = *(const float4*)(xn + (size_t)col0 * D_DIM + lane * 4);
    const float4 a1 = *(const float4*)(xn + (size_t)row1 * D_DIM + lane * 4);
    const float4 b1 = *(const float4*)(xn + (size_t)col1 * D_DIM + lane * 4);
    double d0 = (double)a0.x * b0.x + (double)a0.y * b0.y +
                (double)a0.z * b0.z + (double)a0.w * b0.w;
    double d1 = (double)a1.x * b1.x + (double)a1.y * b1.y +
                (double)a1.z * b1.z + (double)a1.w * b1.w;
    for (int m = 16; m; m >>= 1) {
        d0 += __shfl_xor(d0, m, 32);
        d1 += __shfl_xor(d1, m, 32);
    }
    if (lane == 0) {
        keep[e0] = ((d0 / (na[row0] * na[col0])) >= PT_THR) ? 1.0f : 0.0f;
    } else if (lane == 1 && has1) {
        keep[e1] = ((d1 / (na[row1] * na[col1])) >= PT_THR) ? 1.0f : 0.0f;
    }
}

extern "C" void kernel_launch(void* const* d_in, const int* in_sizes, int n_in,
                              void* d_out, int out_size, void* d_ws, size_t ws_size,
                              hipStream_t stream) {
    const float* x  = (const float*)d_in[0];
    const int*   ei = (const int*)d_in[1];
    const float* ps = (const float*)d_in[2];
    const float* pd = (const float*)d_in[3];
    const float* po = (const float*)d_in[4];

    const int N = in_sizes[0] / D_DIM;    // 100000
    const int E = in_sizes[1] / 2;        // 640000

    float* xn   = (float*)d_out;                       // [N, D]
    float* keep = (float*)d_out + (size_t)N * D_DIM;   // [E]

    char* ws = (char*)d_ws;
    const int nodeBlocks = (N + 7) / 8;
    const int nbmw = (N + 31) / 32;

    if (ws_size >= (size_t)WS_NEED) {
        double* cd    = (double*)(ws + 0);
        double* na    = (double*)(ws + 800000);
        float* nx     = (float*)(ws + 1600000);
        float* rs     = (float*)(ws + 2000000);
        float* rd     = (float*)(ws + 2400000);
        float* ro     = (float*)(ws + 2800000);
        u16*   e_arr  = (u16*)(ws + 3200000);
        float* pack   = (float*)(ws + 4480000);
        float* cfix   = (float*)(ws + 7680000);
        u32*   bitmap = (u32*)(ws + 8080000);
        int*   flags  = (int*)(ws + 8092800);
        float* G      = (float*)(ws + 8092816);
        u32*   x8d    = (u32*)d_out;   // fp8 table [N,32 dwords], dead before xn write

        node_pre_fp8<<<nodeBlocks, 256, 0, stream>>>(x, ps, pd, po, x8d, nx, rs, rd, ro,
                                                     cd, bitmap, nbmw, flags, G, N);
        edge_sim_fp8<<<(E + 31) / 32, 256, 0, stream>>>(x8d, ei, cd, e_arr, E);
        node_prompt_kernel<<<nodeBlocks, 256, 0, stream>>>(x, cd, ps, pd, po, flags,
                                                           nx, rs, rd, ro,
                                                           xn, na, pack, bitmap, cfix, N);
        edge_fix_scan<<<(E + 255) / 256, 256, 0, stream>>>(x, ei, nx, bitmap, cfix, E);
        node_fix_kernel<<<nodeBlocks, 256, 0, stream>>>(x, cd, cfix, bitmap, ps, pd, po,
                                                        flags, nx, rs, rd, ro,
                                                        xn, na, pack, N);
        edge_prune_fused<<<(E + 255) / 256, 256, 0, stream>>>(ei, e_arr, pack, G,
                                                              xn, na, keep, E);
    } else {
        // fallback: proven bf16 pipeline, exact prune (needs ~1.6 MB ws)
        double* cd    = (double*)(ws + 0);
        double* na    = (double*)(ws + 800000);
        int*    flags = (int*)(ws + 1600000);
        u16*    xnorm = (u16*)d_out;

        node_pre_bf16<<<nodeBlocks, 256, 0, stream>>>(x, ps, pd, po, xnorm, cd, flags, N);
        edge_sim_bf16<<<(E + 31) / 32, 256, 0, stream>>>(xnorm, ei, cd, E);
        node_prompt_fb<<<nodeBlocks, 256, 0, stream>>>(x, cd, ps, pd, po, flags, xn, na, N);
        edge_prune_exact<<<(E + 15) / 16, 256, 0, stream>>>(xn, ei, na, keep, E);
    }
}

// Round 9
// 108.610 us; speedup vs baseline: 1.0641x; 1.0641x over previous
//
#include <hip/hip_runtime.h>
#include <hip/hip_bf16.h>
#include <math.h>

#define D_DIM 128
#define SIM_THR 0.2f
#define DEG_THR 3.0f
#define PT_THR 0.1
#define EPS_CS 1e-8
#define NODE_MARGIN 8e-3f    // 5.7 sigma of int8 csim error
#define PRUNE_MARGIN 8e-3f   // 5.7 sigma of int8 edge-cos error
#define PK 4294967296.0      // 2^32: deg-count scale inside packed f64 atomic

typedef unsigned short u16;
typedef unsigned int u32;

// ---------------- primary ws layout (bytes) ----------------
// 0        cd      double[N]  800000  (zeroed by node_pre; packed deg*2^32+c)
// 800000   na      double[N]  800000
// 1600000  nx      f32[N]     400000
// 2000000  r_s     f32[N]     400000
// 2400000  r_d     f32[N]     400000
// 2800000  r_o     f32[N]     400000
// 3200000  sc      f32[N]     400000   (int8 per-row scale)
// 3600000  e_arr   f32[E]     2560000
// 6160000  pack    f32[8N]    3200000  {r_s,r_d,r_o,|x|, as,ad,ao,inv_na}
// 9360000  cfix    f32[N]     400000   (zeroed lazily per flagged node)
// 9760000  bitmap  u32[3125]  12800    (zeroed by node_pre)
// 9772800  flags   int[4]
// 9772816  G       f32[9]
// 9772852  flagcnt int
#define WS_NEED 9772860

__device__ __forceinline__ float bf2f(u16 u) {
    return __uint_as_float(((u32)u) << 16);
}
__device__ __forceinline__ u16 f2bf(float f) {
    __hip_bfloat16 b = __float2bfloat16(f);
    return *(u16*)&b;
}
__device__ __forceinline__ int dot4i8(u32 a, u32 b, int acc) {
#if __has_builtin(__builtin_amdgcn_sdot4)
    return __builtin_amdgcn_sdot4(a, b, acc, false);
#else
    acc += (int)(char)(a) * (int)(char)(b);
    acc += (int)(char)(a >> 8) * (int)(char)(b >> 8);
    acc += (int)(char)(a >> 16) * (int)(char)(b >> 16);
    acc += (int)(char)(a >> 24) * (int)(char)(b >> 24);
    return acc;
#endif
}

// ---- K1: per node: int8 row (per-row scale), |x|, r_k; zero cd/bitmap/flagcnt;
//      block 0 wave 0 computes prompt flags + 3x3 Gram ----
__global__ void node_pre_i8(const float* __restrict__ x,
                            const float* __restrict__ ps,
                            const float* __restrict__ pd,
                            const float* __restrict__ po,
                            u32* __restrict__ x8d,
                            float* __restrict__ nx,
                            float* __restrict__ rs,
                            float* __restrict__ rd,
                            float* __restrict__ ro,
                            float* __restrict__ sc,
                            double* __restrict__ cd,
                            u32* __restrict__ bitmap, int nbmw,
                            int* __restrict__ flags,
                            float* __restrict__ G,
                            int* __restrict__ flagcnt, int N) {
    int g = threadIdx.x >> 5;
    int lane = threadIdx.x & 31;
    int n = blockIdx.x * 8 + g;
    int gid = blockIdx.x * 256 + threadIdx.x;
    if (gid < nbmw) bitmap[gid] = 0u;
    if (gid == 0) *flagcnt = 0;
    if (n < N) {
        int off = lane * 4;
        const float4 v = *(const float4*)(x + (size_t)n * D_DIM + off);
        const float4 s = *(const float4*)(ps + off);
        const float4 d = *(const float4*)(pd + off);
        const float4 o = *(const float4*)(po + off);
        float sq = v.x * v.x + v.y * v.y + v.z * v.z + v.w * v.w;
        float drs = v.x * s.x + v.y * s.y + v.z * s.z + v.w * s.w;
        float drd = v.x * d.x + v.y * d.y + v.z * d.z + v.w * d.w;
        float dro = v.x * o.x + v.y * o.y + v.z * o.z + v.w * o.w;
        for (int m = 16; m; m >>= 1) {
            sq += __shfl_xor(sq, m, 32);
            drs += __shfl_xor(drs, m, 32);
            drd += __shfl_xor(drd, m, 32);
            dro += __shfl_xor(dro, m, 32);
        }
        float nrm = sqrtf(sq);
        float inv = 1.0f / nrm;
        float v0 = v.x * inv, v1 = v.y * inv, v2 = v.z * inv, v3 = v.w * inv;
        float mx = fmaxf(fmaxf(fabsf(v0), fabsf(v1)), fmaxf(fabsf(v2), fabsf(v3)));
        for (int m = 16; m; m >>= 1) mx = fmaxf(mx, __shfl_xor(mx, m, 32));
        float scale = fmaxf(mx, 1e-20f) * (1.0f / 127.0f);
        float isc = 1.0f / scale;
        int q0 = __float2int_rn(v0 * isc);
        int q1 = __float2int_rn(v1 * isc);
        int q2 = __float2int_rn(v2 * isc);
        int q3 = __float2int_rn(v3 * isc);
        u32 packed = ((u32)q0 & 255u) | (((u32)q1 & 255u) << 8) |
                     (((u32)q2 & 255u) << 16) | (((u32)q3 & 255u) << 24);
        x8d[(size_t)n * 32 + lane] = packed;
        if (lane == 0) {
            nx[n] = nrm;
            rs[n] = drs;
            rd[n] = drd;
            ro[n] = dro;
            sc[n] = scale;
            cd[n] = 0.0;
        }
    }
    if (blockIdx.x == 0 && threadIdx.x < 64) {
        int t = threadIdx.x;
        float s0 = ps[t], s1 = ps[t + 64];
        float d0 = pd[t], d1 = pd[t + 64];
        float o0 = po[t], o1 = po[t + 64];
        float ss = s0 * s0 + s1 * s1;
        float sd = s0 * d0 + s1 * d1;
        float so = s0 * o0 + s1 * o1;
        float dd = d0 * d0 + d1 * d1;
        float dO = d0 * o0 + d1 * o1;
        float oo = o0 * o0 + o1 * o1;
        for (int m = 32; m; m >>= 1) {
            ss += __shfl_xor(ss, m);
            sd += __shfl_xor(sd, m);
            so += __shfl_xor(so, m);
            dd += __shfl_xor(dd, m);
            dO += __shfl_xor(dO, m);
            oo += __shfl_xor(oo, m);
        }
        unsigned long long zs = __ballot(s0 == 0.0f || s1 == 0.0f);
        unsigned long long zd = __ballot(d0 == 0.0f || d1 == 0.0f);
        unsigned long long zo = __ballot(o0 == 0.0f || o1 == 0.0f);
        if (t == 0) {
            flags[0] = (zs == 0ull);
            flags[1] = (zd == 0ull);
            flags[2] = (zo == 0ull);
            G[0] = ss; G[1] = sd; G[2] = so;
            G[3] = sd; G[4] = dd; G[5] = dO;
            G[6] = so; G[7] = dO; G[8] = oo;
        }
    }
}

// ---- K2: int8 edge sim, 4 edges per 32-lane group; exact int32 dot,
//      e = idot*sc_r*sc_c; packed f64 atomic per edge ----
__global__ void edge_sim_i8(const u32* __restrict__ x8d,
                            const int* __restrict__ ei,
                            const float* __restrict__ sc,
                            double* __restrict__ cd,
                            float* __restrict__ e_arr,
                            int E) {
    int lane = threadIdx.x & 31;
    int grp = blockIdx.x * 8 + (threadIdx.x >> 5);
    int base = grp * 4;
    if (base >= E) return;

    int r[4], c4[4];
    #pragma unroll
    for (int k = 0; k < 4; ++k) {
        int e = base + k;
        int src = (e < E) ? e : base;
        r[k] = ei[src];
        c4[k] = ei[E + src];
    }
    u32 a[4], b[4];
    #pragma unroll
    for (int k = 0; k < 4; ++k) {
        a[k] = x8d[(size_t)r[k] * 32 + lane];
        b[k] = x8d[(size_t)c4[k] * 32 + lane];
    }
    int d[4];
    #pragma unroll
    for (int k = 0; k < 4; ++k) d[k] = dot4i8(a[k], b[k], 0);
    for (int m = 16; m; m >>= 1) {
        #pragma unroll
        for (int k = 0; k < 4; ++k) d[k] += __shfl_xor(d[k], m, 32);
    }
    if (lane < 4) {
        int e = base + lane;
        if (e < E) {
            int idot = (lane == 0) ? d[0] : (lane == 1) ? d[1]
                     : (lane == 2) ? d[2] : d[3];
            int rr = r[lane], cc = c4[lane];
            float ev = (float)idot * sc[rr] * sc[cc];
            e_arr[e] = ev;
            atomicAdd(&cd[cc], (double)ev + PK);
        }
    }
}

// ---- K3: masks -> x_new; na; pack; flag borderline-csim nodes ----
__global__ void node_prompt_kernel(const float* __restrict__ x,
                                   const double* __restrict__ cd,
                                   const float* __restrict__ ps,
                                   const float* __restrict__ pd,
                                   const float* __restrict__ po,
                                   const int* __restrict__ flags,
                                   const float* __restrict__ nx,
                                   const float* __restrict__ rs,
                                   const float* __restrict__ rd,
                                   const float* __restrict__ ro,
                                   float* __restrict__ xn,
                                   double* __restrict__ na,
                                   float* __restrict__ pack,
                                   u32* __restrict__ bitmap,
                                   float* __restrict__ cfix,
                                   int* __restrict__ flagcnt, int N) {
    int g = threadIdx.x >> 5;
    int lane = threadIdx.x & 31;
    int n = blockIdx.x * 8 + g;
    if (n >= N) return;
    double v = cd[n];
    double degd = floor(v * (1.0 / PK) + 0.5);
    float dg = (float)degd;
    float cc = (float)(v - degd * PK);
    float csim = (dg > 0.0f) ? (cc / fmaxf(dg, 1.0f)) : INFINITY;
    bool ms = (csim <= SIM_THR);
    bool md = (dg <= DEG_THR);
    bool mo = !(ms || md);
    int plen = (ms && flags[0]) + (md && flags[1]) + (mo && flags[2]);
    float invp = (plen > 0) ? (1.0f / (float)plen) : 0.0f;

    int off = lane * 4;
    const float4 xv = *(const float4*)(x + (size_t)n * D_DIM + off);
    const float4 s  = *(const float4*)(ps + off);
    const float4 dd = *(const float4*)(pd + off);
    const float4 o  = *(const float4*)(po + off);

    float4 f;
    f.x = (ms ? s.x : 0.0f) + (md ? dd.x : 0.0f) + (mo ? o.x : 0.0f);
    f.y = (ms ? s.y : 0.0f) + (md ? dd.y : 0.0f) + (mo ? o.y : 0.0f);
    f.z = (ms ? s.z : 0.0f) + (md ? dd.z : 0.0f) + (mo ? o.z : 0.0f);
    f.w = (ms ? s.w : 0.0f) + (md ? dd.w : 0.0f) + (mo ? o.w : 0.0f);

    float4 r;
    r.x = xv.x + f.x * invp;
    r.y = xv.y + f.y * invp;
    r.z = xv.z + f.z * invp;
    r.w = xv.w + f.w * invp;

    *(float4*)(xn + (size_t)n * D_DIM + off) = r;

    double sq = (double)r.x * r.x + (double)r.y * r.y + (double)r.z * r.z + (double)r.w * r.w;
    for (int m = 16; m; m >>= 1) sq += __shfl_xor(sq, m, 32);
    if (lane == 0) {
        double nrm = sqrt(sq);
        double nad = (nrm > EPS_CS) ? nrm : EPS_CS;
        na[n] = nad;
        float as = ms ? invp : 0.0f;
        float ad = md ? invp : 0.0f;
        float ao = mo ? invp : 0.0f;
        *(float4*)(pack + (size_t)n * 8)     = make_float4(rs[n], rd[n], ro[n], nx[n]);
        *(float4*)(pack + (size_t)n * 8 + 4) = make_float4(as, ad, ao, (float)(1.0 / nad));
        if (dg > 0.0f && fabsf(csim - SIM_THR) < NODE_MARGIN) {
            cfix[n] = 0.0f;
            atomicOr(&bitmap[n >> 5], 1u << (n & 31));
            atomicAdd(flagcnt, 1);
        }
    }
}

// ---- K4: rescan edges; recompute e exactly for edges into flagged nodes
//      (early-out when nothing flagged) ----
__global__ void edge_fix_scan(const float* __restrict__ x,
                              const int* __restrict__ ei,
                              const float* __restrict__ nx,
                              const u32* __restrict__ bitmap,
                              const int* __restrict__ flagcnt,
                              float* __restrict__ cfix, int E) {
    if (*flagcnt == 0) return;
    int e = blockIdx.x * 256 + threadIdx.x;
    if (e >= E) return;
    int col = ei[E + e];
    if (!((bitmap[col >> 5] >> (col & 31)) & 1u)) return;
    int row = ei[e];
    const float4* xr = (const float4*)(x + (size_t)row * D_DIM);
    const float4* xc = (const float4*)(x + (size_t)col * D_DIM);
    double s = 0.0;
    for (int i = 0; i < 32; ++i) {
        float4 a = xr[i], b = xc[i];
        s += (double)a.x * b.x + (double)a.y * b.y +
             (double)a.z * b.z + (double)a.w * b.w;
    }
    float ev = (float)(s / ((double)nx[row] * (double)nx[col]));
    atomicAdd(&cfix[col], ev);
}

// ---- K5: rewrite xn/na/pack for flagged nodes using exact csim ----
__global__ void node_fix_kernel(const float* __restrict__ x,
                                const double* __restrict__ cd,
                                const float* __restrict__ cfix,
                                const u32* __restrict__ bitmap,
                                const int* __restrict__ flagcnt,
                                const float* __restrict__ ps,
                                const float* __restrict__ pd,
                                const float* __restrict__ po,
                                const int* __restrict__ flags,
                                const float* __restrict__ nx,
                                const float* __restrict__ rs,
                                const float* __restrict__ rd,
                                const float* __restrict__ ro,
                                float* __restrict__ xn,
                                double* __restrict__ na,
                                float* __restrict__ pack, int N) {
    if (*flagcnt == 0) return;
    int g = threadIdx.x >> 5;
    int lane = threadIdx.x & 31;
    int n = blockIdx.x * 8 + g;
    if (n >= N) return;
    if (!((bitmap[n >> 5] >> (n & 31)) & 1u)) return;

    double v = cd[n];
    double degd = floor(v * (1.0 / PK) + 0.5);
    float dg = (float)degd;                 // flagged => dg > 0
    float csim = cfix[n] / fmaxf(dg, 1.0f);
    bool ms = (csim <= SIM_THR);
    bool md = (dg <= DEG_THR);
    bool mo = !(ms || md);
    int plen = (ms && flags[0]) + (md && flags[1]) + (mo && flags[2]);
    float invp = (plen > 0) ? (1.0f / (float)plen) : 0.0f;

    int off = lane * 4;
    const float4 xv = *(const float4*)(x + (size_t)n * D_DIM + off);
    const float4 s  = *(const float4*)(ps + off);
    const float4 dd = *(const float4*)(pd + off);
    const float4 o  = *(const float4*)(po + off);

    float4 f;
    f.x = (ms ? s.x : 0.0f) + (md ? dd.x : 0.0f) + (mo ? o.x : 0.0f);
    f.y = (ms ? s.y : 0.0f) + (md ? dd.y : 0.0f) + (mo ? o.y : 0.0f);
    f.z = (ms ? s.z : 0.0f) + (md ? dd.z : 0.0f) + (mo ? o.z : 0.0f);
    f.w = (ms ? s.w : 0.0f) + (md ? dd.w : 0.0f) + (mo ? o.w : 0.0f);

    float4 r;
    r.x = xv.x + f.x * invp;
    r.y = xv.y + f.y * invp;
    r.z = xv.z + f.z * invp;
    r.w = xv.w + f.w * invp;

    *(float4*)(xn + (size_t)n * D_DIM + off) = r;

    double sq = (double)r.x * r.x + (double)r.y * r.y + (double)r.z * r.z + (double)r.w * r.w;
    for (int m = 16; m; m >>= 1) sq += __shfl_xor(sq, m, 32);
    if (lane == 0) {
        double nrm = sqrt(sq);
        double nad = (nrm > EPS_CS) ? nrm : EPS_CS;
        na[n] = nad;
        float as = ms ? invp : 0.0f;
        float ad = md ? invp : 0.0f;
        float ao = mo ? invp : 0.0f;
        *(float4*)(pack + (size_t)n * 8)     = make_float4(rs[n], rd[n], ro[n], nx[n]);
        *(float4*)(pack + (size_t)n * 8 + 4) = make_float4(as, ad, ao, (float)(1.0 / nad));
    }
}

// ---- K6: fused factored prune + in-block exact fixup (overflow-safe) ----
__global__ void edge_prune_fused(const int* __restrict__ ei,
                                 const float* __restrict__ e_arr,
                                 const float* __restrict__ pack,
                                 const float* __restrict__ G,
                                 const float* __restrict__ xn,
                                 const double* __restrict__ na,
                                 float* __restrict__ keep, int E) {
    __shared__ int s_list[256];
    __shared__ int s_cnt;
    int tid = threadIdx.x;
    if (tid == 0) s_cnt = 0;
    __syncthreads();

    int e = blockIdx.x * 256 + tid;
    if (e < E) {
        int i = ei[e], j = ei[E + e];
        const float4 ri = *(const float4*)(pack + (size_t)i * 8);
        const float4 ai = *(const float4*)(pack + (size_t)i * 8 + 4);
        const float4 rj = *(const float4*)(pack + (size_t)j * 8);
        const float4 aj = *(const float4*)(pack + (size_t)j * 8 + 4);
        float ev = e_arr[e];
        float dot = ev * ri.w * rj.w
                  + aj.x * ri.x + aj.y * ri.y + aj.z * ri.z
                  + ai.x * rj.x + ai.y * rj.y + ai.z * rj.z;
        dot += ai.x * (G[0] * aj.x + G[1] * aj.y + G[2] * aj.z)
             + ai.y * (G[3] * aj.x + G[4] * aj.y + G[5] * aj.z)
             + ai.z * (G[6] * aj.x + G[7] * aj.y + G[8] * aj.z);
        float cosv = dot * ai.w * aj.w;
        keep[e] = (cosv >= 0.1f) ? 1.0f : 0.0f;
        if (fabsf(cosv - 0.1f) < PRUNE_MARGIN) {
            int idx = atomicAdd(&s_cnt, 1);
            if (idx < 256) {
                s_list[idx] = e;
            } else {
                const float4* xr = (const float4*)(xn + (size_t)i * D_DIM);
                const float4* xc = (const float4*)(xn + (size_t)j * D_DIM);
                double sd = 0.0;
                for (int it = 0; it < 32; ++it) {
                    float4 a = xr[it], b = xc[it];
                    sd += (double)a.x * b.x + (double)a.y * b.y +
                          (double)a.z * b.z + (double)a.w * b.w;
                }
                double cs = sd / (na[i] * na[j]);
                keep[e] = (cs >= PT_THR) ? 1.0f : 0.0f;
            }
        }
    }
    __syncthreads();

    int cnt = s_cnt < 256 ? s_cnt : 256;
    int lane = tid & 31;
    int grp = tid >> 5;
    for (int it = grp; it < cnt; it += 8) {
        int ee = s_list[it];
        int row = ei[ee], col = ei[E + ee];
        const float4 a = *(const float4*)(xn + (size_t)row * D_DIM + lane * 4);
        const float4 b = *(const float4*)(xn + (size_t)col * D_DIM + lane * 4);
        double d = (double)a.x * b.x + (double)a.y * b.y +
                   (double)a.z * b.z + (double)a.w * b.w;
        for (int m = 16; m; m >>= 1) d += __shfl_xor(d, m, 32);
        if (lane == 0) {
            double cs = d / (na[row] * na[col]);
            keep[ee] = (cs >= PT_THR) ? 1.0f : 0.0f;
        }
    }
}

// ================= fallback path (small ws): bf16 pipeline, exact prune ====
__global__ void node_pre_bf16(const float* __restrict__ x,
                              const float* __restrict__ ps,
                              const float* __restrict__ pd,
                              const float* __restrict__ po,
                              u16* __restrict__ xnorm,
                              double* __restrict__ cd,
                              int* __restrict__ flags, int N) {
    int g = threadIdx.x >> 5;
    int lane = threadIdx.x & 31;
    int n = blockIdx.x * 8 + g;
    if (n < N) {
        int off = lane * 4;
        const float4 v = *(const float4*)(x + (size_t)n * D_DIM + off);
        float sq = v.x * v.x + v.y * v.y + v.z * v.z + v.w * v.w;
        for (int m = 16; m; m >>= 1) sq += __shfl_xor(sq, m, 32);
        float inv = 1.0f / sqrtf(sq);
        *(ushort4*)(xnorm + (size_t)n * D_DIM + off) =
            make_ushort4(f2bf(v.x * inv), f2bf(v.y * inv), f2bf(v.z * inv), f2bf(v.w * inv));
        if (lane == 0) cd[n] = 0.0;
    }
    if (blockIdx.x == 0 && threadIdx.x < 64) {
        int t = threadIdx.x;
        unsigned long long zs = __ballot(ps[t] == 0.0f || ps[t + 64] == 0.0f);
        unsigned long long zd = __ballot(pd[t] == 0.0f || pd[t + 64] == 0.0f);
        unsigned long long zo = __ballot(po[t] == 0.0f || po[t + 64] == 0.0f);
        if (t == 0) {
            flags[0] = (zs == 0ull);
            flags[1] = (zd == 0ull);
            flags[2] = (zo == 0ull);
        }
    }
}

__global__ void edge_sim_bf16(const u16* __restrict__ xnorm,
                              const int* __restrict__ ei,
                              double* __restrict__ cd, int E) {
    int lane = threadIdx.x & 31;
    int grp = blockIdx.x * 8 + (threadIdx.x >> 5);
    int base = grp * 4;
    if (base >= E) return;
    int r[4], c4[4];
    #pragma unroll
    for (int k = 0; k < 4; ++k) {
        int e = base + k;
        int src = (e < E) ? e : base;
        r[k] = ei[src];
        c4[k] = ei[E + src];
    }
    float d[4];
    #pragma unroll
    for (int k = 0; k < 4; ++k) {
        ushort4 a = *(const ushort4*)(xnorm + (size_t)r[k] * D_DIM + lane * 4);
        ushort4 b = *(const ushort4*)(xnorm + (size_t)c4[k] * D_DIM + lane * 4);
        d[k] = bf2f(a.x) * bf2f(b.x) + bf2f(a.y) * bf2f(b.y) +
               bf2f(a.z) * bf2f(b.z) + bf2f(a.w) * bf2f(b.w);
    }
    for (int m = 16; m; m >>= 1) {
        #pragma unroll
        for (int k = 0; k < 4; ++k) d[k] += __shfl_xor(d[k], m, 32);
    }
    if (lane < 4) {
        int e = base + lane;
        if (e < E) {
            float dv = (lane == 0) ? d[0] : (lane == 1) ? d[1]
                     : (lane == 2) ? d[2] : d[3];
            atomicAdd(&cd[c4[lane]], (double)dv + PK);
        }
    }
}

__global__ void node_prompt_fb(const float* __restrict__ x,
                               const double* __restrict__ cd,
                               const float* __restrict__ ps,
                               const float* __restrict__ pd,
                               const float* __restrict__ po,
                               const int* __restrict__ flags,
                               float* __restrict__ xn,
                               double* __restrict__ na, int N) {
    int g = threadIdx.x >> 5;
    int lane = threadIdx.x & 31;
    int n = blockIdx.x * 8 + g;
    if (n >= N) return;
    double v = cd[n];
    double degd = floor(v * (1.0 / PK) + 0.5);
    float dg = (float)degd;
    float cc = (float)(v - degd * PK);
    float csim = (dg > 0.0f) ? (cc / fmaxf(dg, 1.0f)) : INFINITY;
    bool ms = (csim <= SIM_THR);
    bool md = (dg <= DEG_THR);
    bool mo = !(ms || md);
    int plen = (ms && flags[0]) + (md && flags[1]) + (mo && flags[2]);
    float invp = (plen > 0) ? (1.0f / (float)plen) : 0.0f;
    int off = lane * 4;
    const float4 xv = *(const float4*)(x + (size_t)n * D_DIM + off);
    const float4 s  = *(const float4*)(ps + off);
    const float4 dd = *(const float4*)(pd + off);
    const float4 o  = *(const float4*)(po + off);
    float4 r;
    r.x = xv.x + ((ms ? s.x : 0.0f) + (md ? dd.x : 0.0f) + (mo ? o.x : 0.0f)) * invp;
    r.y = xv.y + ((ms ? s.y : 0.0f) + (md ? dd.y : 0.0f) + (mo ? o.y : 0.0f)) * invp;
    r.z = xv.z + ((ms ? s.z : 0.0f) + (md ? dd.z : 0.0f) + (mo ? o.z : 0.0f)) * invp;
    r.w = xv.w + ((ms ? s.w : 0.0f) + (md ? dd.w : 0.0f) + (mo ? o.w : 0.0f)) * invp;
    *(float4*)(xn + (size_t)n * D_DIM + off) = r;
    double sq = (double)r.x * r.x + (double)r.y * r.y + (double)r.z * r.z + (double)r.w * r.w;
    for (int m = 16; m; m >>= 1) sq += __shfl_xor(sq, m, 32);
    if (lane == 0) {
        double nrm = sqrt(sq);
        na[n] = (nrm > EPS_CS) ? nrm : EPS_CS;
    }
}

__global__ void edge_prune_exact(const float* __restrict__ xn,
                                 const int* __restrict__ ei,
                                 const double* __restrict__ na,
                                 float* __restrict__ keep, int E) {
    int lane = threadIdx.x & 31;
    int grp = blockIdx.x * 8 + (threadIdx.x >> 5);
    int e0 = grp * 2, e1 = e0 + 1;
    if (e0 >= E) return;
    bool has1 = (e1 < E);
    int row0 = ei[e0], col0 = ei[E + e0];
    int row1 = has1 ? ei[e1] : row0;
    int col1 = has1 ? ei[E + e1] : col0;
    const float4 a0 = *(const float4*)(xn + (size_t)row0 * D_DIM + lane * 4);
    const float4 b0 = *(const float4*)(xn + (size_t)col0 * D_DIM + lane * 4);
    const float4 a1 = *(const float4*)(xn + (size_t)row1 * D_DIM + lane * 4);
    const float4 b1 = *(const float4*)(xn + (size_t)col1 * D_DIM + lane * 4);
    double d0 = (double)a0.x * b0.x + (double)a0.y * b0.y +
                (double)a0.z * b0.z + (double)a0.w * b0.w;
    double d1 = (double)a1.x * b1.x + (double)a1.y * b1.y +
                (double)a1.z * b1.z + (double)a1.w * b1.w;
    for (int m = 16; m; m >>= 1) {
        d0 += __shfl_xor(d0, m, 32);
        d1 += __shfl_xor(d1, m, 32);
    }
    if (lane == 0) {
        keep[e0] = ((d0 / (na[row0] * na[col0])) >= PT_THR) ? 1.0f : 0.0f;
    } else if (lane == 1 && has1) {
        keep[e1] = ((d1 / (na[row1] * na[col1])) >= PT_THR) ? 1.0f : 0.0f;
    }
}

extern "C" void kernel_launch(void* const* d_in, const int* in_sizes, int n_in,
                              void* d_out, int out_size, void* d_ws, size_t ws_size,
                              hipStream_t stream) {
    const float* x  = (const float*)d_in[0];
    const int*   ei = (const int*)d_in[1];
    const float* ps = (const float*)d_in[2];
    const float* pd = (const float*)d_in[3];
    const float* po = (const float*)d_in[4];

    const int N = in_sizes[0] / D_DIM;    // 100000
    const int E = in_sizes[1] / 2;        // 640000

    float* xn   = (float*)d_out;                       // [N, D]
    float* keep = (float*)d_out + (size_t)N * D_DIM;   // [E]

    char* ws = (char*)d_ws;
    const int nodeBlocks = (N + 7) / 8;
    const int nbmw = (N + 31) / 32;

    if (ws_size >= (size_t)WS_NEED) {
        double* cd     = (double*)(ws + 0);
        double* na     = (double*)(ws + 800000);
        float* nx      = (float*)(ws + 1600000);
        float* rs      = (float*)(ws + 2000000);
        float* rd      = (float*)(ws + 2400000);
        float* ro      = (float*)(ws + 2800000);
        float* sc      = (float*)(ws + 3200000);
        float* e_arr   = (float*)(ws + 3600000);
        float* pack    = (float*)(ws + 6160000);
        float* cfix    = (float*)(ws + 9360000);
        u32*   bitmap  = (u32*)(ws + 9760000);
        int*   flags   = (int*)(ws + 9772800);
        float* G       = (float*)(ws + 9772816);
        int*   flagcnt = (int*)(ws + 9772852);
        u32*   x8d     = (u32*)d_out;   // int8 table [N,32 dwords], dead before xn write

        node_pre_i8<<<nodeBlocks, 256, 0, stream>>>(x, ps, pd, po, x8d, nx, rs, rd, ro,
                                                    sc, cd, bitmap, nbmw, flags, G,
                                                    flagcnt, N);
        edge_sim_i8<<<(E + 31) / 32, 256, 0, stream>>>(x8d, ei, sc, cd, e_arr, E);
        node_prompt_kernel<<<nodeBlocks, 256, 0, stream>>>(x, cd, ps, pd, po, flags,
                                                           nx, rs, rd, ro,
                                                           xn, na, pack, bitmap, cfix,
                                                           flagcnt, N);
        edge_fix_scan<<<(E + 255) / 256, 256, 0, stream>>>(x, ei, nx, bitmap, flagcnt,
                                                           cfix, E);
        node_fix_kernel<<<nodeBlocks, 256, 0, stream>>>(x, cd, cfix, bitmap, flagcnt,
                                                        ps, pd, po, flags, nx, rs, rd, ro,
                                                        xn, na, pack, N);
        edge_prune_fused<<<(E + 255) / 256, 256, 0, stream>>>(ei, e_arr, pack, G,
                                                              xn, na, keep, E);
    } else {
        // fallback: proven bf16 pipeline, exact prune (needs ~1.6 MB ws)
        double* cd    = (double*)(ws + 0);
        double* na    = (double*)(ws + 800000);
        int*    flags = (int*)(ws + 1600000);
        u16*    xnorm = (u16*)d_out;

        node_pre_bf16<<<nodeBlocks, 256, 0, stream>>>(x, ps, pd, po, xnorm, cd, flags, N);
        edge_sim_bf16<<<(E + 31) / 32, 256, 0, stream>>>(xnorm, ei, cd, E);
        node_prompt_fb<<<nodeBlocks, 256, 0, stream>>>(x, cd, ps, pd, po, flags, xn, na, N);
        edge_prune_exact<<<(E + 15) / 16, 256, 0, stream>>>(xn, ei, na, keep, E);
    }
}

// Round 10
// 107.580 us; speedup vs baseline: 1.0743x; 1.0096x over previous
//
#include <hip/hip_runtime.h>
#include <hip/hip_bf16.h>
#include <math.h>

#define D_DIM 128
#define SIM_THR 0.2f
#define DEG_THR 3.0f
#define PT_THR 0.1
#define EPS_CS 1e-8
#define NODE_MARGIN 8e-3f    // ~8 sigma of int8 csim error
#define PRUNE_MARGIN 8e-3f   // ~8 sigma of int8 edge-cos error
#define PK 4294967296.0      // 2^32: deg-count scale inside packed f64 atomic

typedef unsigned short u16;
typedef unsigned int u32;

// ---------------- primary ws layout (bytes) ----------------
// 0        cd      double[N]  800000  (zeroed by node_pre; packed deg*2^32+c)
// 800000   na      double[N]  800000
// 1600000  nx      f32[N]     400000
// 2000000  r_s     f32[N]     400000
// 2400000  r_d     f32[N]     400000
// 2800000  r_o     f32[N]     400000
// 3200000  sc      f32[N]     400000   (int8 per-row scale)
// 3600000  e_arr   f32[E]     2560000
// 6160000  pack    f32[8N]    3200000  {r_s,r_d,r_o,|x|, as,ad,ao,inv_na}
// 9360000  cfix    f32[N]     400000   (zeroed lazily per flagged node)
// 9760000  bitmap  u32[3125]  12800    (zeroed by node_pre)
// 9772800  flags   int[4]
// 9772816  G       f32[9]
// 9772852  flagcnt int
#define WS_NEED 9772860

__device__ __forceinline__ float bf2f(u16 u) {
    return __uint_as_float(((u32)u) << 16);
}
__device__ __forceinline__ u16 f2bf(float f) {
    __hip_bfloat16 b = __float2bfloat16(f);
    return *(u16*)&b;
}
__device__ __forceinline__ int dot4i8(u32 a, u32 b, int acc) {
#if __has_builtin(__builtin_amdgcn_sdot4)
    return __builtin_amdgcn_sdot4(a, b, acc, false);
#else
    acc += (int)(char)(a) * (int)(char)(b);
    acc += (int)(char)(a >> 8) * (int)(char)(b >> 8);
    acc += (int)(char)(a >> 16) * (int)(char)(b >> 16);
    acc += (int)(char)(a >> 24) * (int)(char)(b >> 24);
    return acc;
#endif
}

// ---- K1: per node: int8 row (per-row scale), |x|, r_k; zero cd/bitmap/flagcnt;
//      block 0 wave 0 computes prompt flags + 3x3 Gram ----
__global__ void node_pre_i8(const float* __restrict__ x,
                            const float* __restrict__ ps,
                            const float* __restrict__ pd,
                            const float* __restrict__ po,
                            u32* __restrict__ x8d,
                            float* __restrict__ nx,
                            float* __restrict__ rs,
                            float* __restrict__ rd,
                            float* __restrict__ ro,
                            float* __restrict__ sc,
                            double* __restrict__ cd,
                            u32* __restrict__ bitmap, int nbmw,
                            int* __restrict__ flags,
                            float* __restrict__ G,
                            int* __restrict__ flagcnt, int N) {
    int g = threadIdx.x >> 5;
    int lane = threadIdx.x & 31;
    int n = blockIdx.x * 8 + g;
    int gid = blockIdx.x * 256 + threadIdx.x;
    if (gid < nbmw) bitmap[gid] = 0u;
    if (gid == 0) *flagcnt = 0;
    if (n < N) {
        int off = lane * 4;
        const float4 v = *(const float4*)(x + (size_t)n * D_DIM + off);
        const float4 s = *(const float4*)(ps + off);
        const float4 d = *(const float4*)(pd + off);
        const float4 o = *(const float4*)(po + off);
        float sq = v.x * v.x + v.y * v.y + v.z * v.z + v.w * v.w;
        float drs = v.x * s.x + v.y * s.y + v.z * s.z + v.w * s.w;
        float drd = v.x * d.x + v.y * d.y + v.z * d.z + v.w * d.w;
        float dro = v.x * o.x + v.y * o.y + v.z * o.z + v.w * o.w;
        for (int m = 16; m; m >>= 1) {
            sq += __shfl_xor(sq, m, 32);
            drs += __shfl_xor(drs, m, 32);
            drd += __shfl_xor(drd, m, 32);
            dro += __shfl_xor(dro, m, 32);
        }
        float nrm = sqrtf(sq);
        float inv = 1.0f / nrm;
        float v0 = v.x * inv, v1 = v.y * inv, v2 = v.z * inv, v3 = v.w * inv;
        float mx = fmaxf(fmaxf(fabsf(v0), fabsf(v1)), fmaxf(fabsf(v2), fabsf(v3)));
        for (int m = 16; m; m >>= 1) mx = fmaxf(mx, __shfl_xor(mx, m, 32));
        float scale = fmaxf(mx, 1e-20f) * (1.0f / 127.0f);
        float isc = 1.0f / scale;
        int q0 = __float2int_rn(v0 * isc);
        int q1 = __float2int_rn(v1 * isc);
        int q2 = __float2int_rn(v2 * isc);
        int q3 = __float2int_rn(v3 * isc);
        u32 packed = ((u32)q0 & 255u) | (((u32)q1 & 255u) << 8) |
                     (((u32)q2 & 255u) << 16) | (((u32)q3 & 255u) << 24);
        x8d[(size_t)n * 32 + lane] = packed;
        if (lane == 0) {
            nx[n] = nrm;
            rs[n] = drs;
            rd[n] = drd;
            ro[n] = dro;
            sc[n] = scale;
            cd[n] = 0.0;
        }
    }
    if (blockIdx.x == 0 && threadIdx.x < 64) {
        int t = threadIdx.x;
        float s0 = ps[t], s1 = ps[t + 64];
        float d0 = pd[t], d1 = pd[t + 64];
        float o0 = po[t], o1 = po[t + 64];
        float ss = s0 * s0 + s1 * s1;
        float sd = s0 * d0 + s1 * d1;
        float so = s0 * o0 + s1 * o1;
        float dd = d0 * d0 + d1 * d1;
        float dO = d0 * o0 + d1 * o1;
        float oo = o0 * o0 + o1 * o1;
        for (int m = 32; m; m >>= 1) {
            ss += __shfl_xor(ss, m);
            sd += __shfl_xor(sd, m);
            so += __shfl_xor(so, m);
            dd += __shfl_xor(dd, m);
            dO += __shfl_xor(dO, m);
            oo += __shfl_xor(oo, m);
        }
        unsigned long long zs = __ballot(s0 == 0.0f || s1 == 0.0f);
        unsigned long long zd = __ballot(d0 == 0.0f || d1 == 0.0f);
        unsigned long long zo = __ballot(o0 == 0.0f || o1 == 0.0f);
        if (t == 0) {
            flags[0] = (zs == 0ull);
            flags[1] = (zd == 0ull);
            flags[2] = (zo == 0ull);
            G[0] = ss; G[1] = sd; G[2] = so;
            G[3] = sd; G[4] = dd; G[5] = dO;
            G[6] = so; G[7] = dO; G[8] = oo;
        }
    }
}

// ---- K2: int8 edge sim, 16 lanes/row (uint2 = 8B/lane), 8 edges per
//      32-lane group (4 per half) -> 1 load-instr/edge; exact int32 dot ----
__global__ void edge_sim_i8(const u32* __restrict__ x8d,
                            const int* __restrict__ ei,
                            const float* __restrict__ sc,
                            double* __restrict__ cd,
                            float* __restrict__ e_arr,
                            int E) {
    int lane = threadIdx.x & 31;
    int half = lane >> 4;        // 0 or 1: which 4-edge batch of this group
    int sub  = lane & 15;        // position within the 16-lane row slice
    int grp = blockIdx.x * 8 + (threadIdx.x >> 5);
    int base = grp * 8;
    if (base >= E) return;
    int eb = base + half * 4;

    int r[4], c4[4];
    #pragma unroll
    for (int k = 0; k < 4; ++k) {
        int e = eb + k;
        int src = (e < E) ? e : base;
        r[k] = ei[src];
        c4[k] = ei[E + src];
    }
    uint2 a[4], b[4];
    #pragma unroll
    for (int k = 0; k < 4; ++k) {
        a[k] = *(const uint2*)(x8d + (size_t)r[k] * 32 + sub * 2);
        b[k] = *(const uint2*)(x8d + (size_t)c4[k] * 32 + sub * 2);
    }
    int d[4];
    #pragma unroll
    for (int k = 0; k < 4; ++k)
        d[k] = dot4i8(a[k].y, b[k].y, dot4i8(a[k].x, b[k].x, 0));
    // butterfly over 16-lane half (masks 1,2,4,8 never cross the half)
    #pragma unroll
    for (int m = 8; m; m >>= 1) {
        #pragma unroll
        for (int k = 0; k < 4; ++k) d[k] += __shfl_xor(d[k], m, 32);
    }
    if (sub < 4) {
        int e = eb + sub;
        if (e < E) {
            int idot = (sub == 0) ? d[0] : (sub == 1) ? d[1]
                     : (sub == 2) ? d[2] : d[3];
            int rr = (sub == 0) ? r[0] : (sub == 1) ? r[1]
                   : (sub == 2) ? r[2] : r[3];
            int cc = (sub == 0) ? c4[0] : (sub == 1) ? c4[1]
                   : (sub == 2) ? c4[2] : c4[3];
            float ev = (float)idot * sc[rr] * sc[cc];
            e_arr[e] = ev;
            atomicAdd(&cd[cc], (double)ev + PK);
        }
    }
}

// ---- K3: masks -> x_new; na; pack; flag borderline-csim nodes ----
__global__ void node_prompt_kernel(const float* __restrict__ x,
                                   const double* __restrict__ cd,
                                   const float* __restrict__ ps,
                                   const float* __restrict__ pd,
                                   const float* __restrict__ po,
                                   const int* __restrict__ flags,
                                   const float* __restrict__ nx,
                                   const float* __restrict__ rs,
                                   const float* __restrict__ rd,
                                   const float* __restrict__ ro,
                                   float* __restrict__ xn,
                                   double* __restrict__ na,
                                   float* __restrict__ pack,
                                   u32* __restrict__ bitmap,
                                   float* __restrict__ cfix,
                                   int* __restrict__ flagcnt, int N) {
    int g = threadIdx.x >> 5;
    int lane = threadIdx.x & 31;
    int n = blockIdx.x * 8 + g;
    if (n >= N) return;
    double v = cd[n];
    double degd = floor(v * (1.0 / PK) + 0.5);
    float dg = (float)degd;
    float cc = (float)(v - degd * PK);
    float csim = (dg > 0.0f) ? (cc / fmaxf(dg, 1.0f)) : INFINITY;
    bool ms = (csim <= SIM_THR);
    bool md = (dg <= DEG_THR);
    bool mo = !(ms || md);
    int plen = (ms && flags[0]) + (md && flags[1]) + (mo && flags[2]);
    float invp = (plen > 0) ? (1.0f / (float)plen) : 0.0f;

    int off = lane * 4;
    const float4 xv = *(const float4*)(x + (size_t)n * D_DIM + off);
    const float4 s  = *(const float4*)(ps + off);
    const float4 dd = *(const float4*)(pd + off);
    const float4 o  = *(const float4*)(po + off);

    float4 f;
    f.x = (ms ? s.x : 0.0f) + (md ? dd.x : 0.0f) + (mo ? o.x : 0.0f);
    f.y = (ms ? s.y : 0.0f) + (md ? dd.y : 0.0f) + (mo ? o.y : 0.0f);
    f.z = (ms ? s.z : 0.0f) + (md ? dd.z : 0.0f) + (mo ? o.z : 0.0f);
    f.w = (ms ? s.w : 0.0f) + (md ? dd.w : 0.0f) + (mo ? o.w : 0.0f);

    float4 r;
    r.x = xv.x + f.x * invp;
    r.y = xv.y + f.y * invp;
    r.z = xv.z + f.z * invp;
    r.w = xv.w + f.w * invp;

    *(float4*)(xn + (size_t)n * D_DIM + off) = r;

    double sq = (double)r.x * r.x + (double)r.y * r.y + (double)r.z * r.z + (double)r.w * r.w;
    for (int m = 16; m; m >>= 1) sq += __shfl_xor(sq, m, 32);
    if (lane == 0) {
        double nrm = sqrt(sq);
        double nad = (nrm > EPS_CS) ? nrm : EPS_CS;
        na[n] = nad;
        float as = ms ? invp : 0.0f;
        float ad = md ? invp : 0.0f;
        float ao = mo ? invp : 0.0f;
        *(float4*)(pack + (size_t)n * 8)     = make_float4(rs[n], rd[n], ro[n], nx[n]);
        *(float4*)(pack + (size_t)n * 8 + 4) = make_float4(as, ad, ao, (float)(1.0 / nad));
        if (dg > 0.0f && fabsf(csim - SIM_THR) < NODE_MARGIN) {
            cfix[n] = 0.0f;
            atomicOr(&bitmap[n >> 5], 1u << (n & 31));
            atomicAdd(flagcnt, 1);
        }
    }
}

// ---- K4: rescan edges; recompute e exactly for edges into flagged nodes
//      (early-out when nothing flagged) ----
__global__ void edge_fix_scan(const float* __restrict__ x,
                              const int* __restrict__ ei,
                              const float* __restrict__ nx,
                              const u32* __restrict__ bitmap,
                              const int* __restrict__ flagcnt,
                              float* __restrict__ cfix, int E) {
    if (*flagcnt == 0) return;
    int e = blockIdx.x * 256 + threadIdx.x;
    if (e >= E) return;
    int col = ei[E + e];
    if (!((bitmap[col >> 5] >> (col & 31)) & 1u)) return;
    int row = ei[e];
    const float4* xr = (const float4*)(x + (size_t)row * D_DIM);
    const float4* xc = (const float4*)(x + (size_t)col * D_DIM);
    double s = 0.0;
    for (int i = 0; i < 32; ++i) {
        float4 a = xr[i], b = xc[i];
        s += (double)a.x * b.x + (double)a.y * b.y +
             (double)a.z * b.z + (double)a.w * b.w;
    }
    float ev = (float)(s / ((double)nx[row] * (double)nx[col]));
    atomicAdd(&cfix[col], ev);
}

// ---- K5: rewrite xn/na/pack for flagged nodes using exact csim ----
__global__ void node_fix_kernel(const float* __restrict__ x,
                                const double* __restrict__ cd,
                                const float* __restrict__ cfix,
                                const u32* __restrict__ bitmap,
                                const int* __restrict__ flagcnt,
                                const float* __restrict__ ps,
                                const float* __restrict__ pd,
                                const float* __restrict__ po,
                                const int* __restrict__ flags,
                                const float* __restrict__ nx,
                                const float* __restrict__ rs,
                                const float* __restrict__ rd,
                                const float* __restrict__ ro,
                                float* __restrict__ xn,
                                double* __restrict__ na,
                                float* __restrict__ pack, int N) {
    if (*flagcnt == 0) return;
    int g = threadIdx.x >> 5;
    int lane = threadIdx.x & 31;
    int n = blockIdx.x * 8 + g;
    if (n >= N) return;
    if (!((bitmap[n >> 5] >> (n & 31)) & 1u)) return;

    double v = cd[n];
    double degd = floor(v * (1.0 / PK) + 0.5);
    float dg = (float)degd;                 // flagged => dg > 0
    float csim = cfix[n] / fmaxf(dg, 1.0f);
    bool ms = (csim <= SIM_THR);
    bool md = (dg <= DEG_THR);
    bool mo = !(ms || md);
    int plen = (ms && flags[0]) + (md && flags[1]) + (mo && flags[2]);
    float invp = (plen > 0) ? (1.0f / (float)plen) : 0.0f;

    int off = lane * 4;
    const float4 xv = *(const float4*)(x + (size_t)n * D_DIM + off);
    const float4 s  = *(const float4*)(ps + off);
    const float4 dd = *(const float4*)(pd + off);
    const float4 o  = *(const float4*)(po + off);

    float4 f;
    f.x = (ms ? s.x : 0.0f) + (md ? dd.x : 0.0f) + (mo ? o.x : 0.0f);
    f.y = (ms ? s.y : 0.0f) + (md ? dd.y : 0.0f) + (mo ? o.y : 0.0f);
    f.z = (ms ? s.z : 0.0f) + (md ? dd.z : 0.0f) + (mo ? o.z : 0.0f);
    f.w = (ms ? s.w : 0.0f) + (md ? dd.w : 0.0f) + (mo ? o.w : 0.0f);

    float4 r;
    r.x = xv.x + f.x * invp;
    r.y = xv.y + f.y * invp;
    r.z = xv.z + f.z * invp;
    r.w = xv.w + f.w * invp;

    *(float4*)(xn + (size_t)n * D_DIM + off) = r;

    double sq = (double)r.x * r.x + (double)r.y * r.y + (double)r.z * r.z + (double)r.w * r.w;
    for (int m = 16; m; m >>= 1) sq += __shfl_xor(sq, m, 32);
    if (lane == 0) {
        double nrm = sqrt(sq);
        double nad = (nrm > EPS_CS) ? nrm : EPS_CS;
        na[n] = nad;
        float as = ms ? invp : 0.0f;
        float ad = md ? invp : 0.0f;
        float ao = mo ? invp : 0.0f;
        *(float4*)(pack + (size_t)n * 8)     = make_float4(rs[n], rd[n], ro[n], nx[n]);
        *(float4*)(pack + (size_t)n * 8 + 4) = make_float4(as, ad, ao, (float)(1.0 / nad));
    }
}

// ---- K6: fused factored prune + in-block exact fixup (overflow-safe) ----
__global__ void edge_prune_fused(const int* __restrict__ ei,
                                 const float* __restrict__ e_arr,
                                 const float* __restrict__ pack,
                                 const float* __restrict__ G,
                                 const float* __restrict__ xn,
                                 const double* __restrict__ na,
                                 float* __restrict__ keep, int E) {
    __shared__ int s_list[256];
    __shared__ int s_cnt;
    int tid = threadIdx.x;
    if (tid == 0) s_cnt = 0;
    __syncthreads();

    int e = blockIdx.x * 256 + tid;
    if (e < E) {
        int i = ei[e], j = ei[E + e];
        const float4 ri = *(const float4*)(pack + (size_t)i * 8);
        const float4 ai = *(const float4*)(pack + (size_t)i * 8 + 4);
        const float4 rj = *(const float4*)(pack + (size_t)j * 8);
        const float4 aj = *(const float4*)(pack + (size_t)j * 8 + 4);
        float ev = e_arr[e];
        float dot = ev * ri.w * rj.w
                  + aj.x * ri.x + aj.y * ri.y + aj.z * ri.z
                  + ai.x * rj.x + ai.y * rj.y + ai.z * rj.z;
        dot += ai.x * (G[0] * aj.x + G[1] * aj.y + G[2] * aj.z)
             + ai.y * (G[3] * aj.x + G[4] * aj.y + G[5] * aj.z)
             + ai.z * (G[6] * aj.x + G[7] * aj.y + G[8] * aj.z);
        float cosv = dot * ai.w * aj.w;
        keep[e] = (cosv >= 0.1f) ? 1.0f : 0.0f;
        if (fabsf(cosv - 0.1f) < PRUNE_MARGIN) {
            int idx = atomicAdd(&s_cnt, 1);
            if (idx < 256) {
                s_list[idx] = e;
            } else {
                const float4* xr = (const float4*)(xn + (size_t)i * D_DIM);
                const float4* xc = (const float4*)(xn + (size_t)j * D_DIM);
                double sd = 0.0;
                for (int it = 0; it < 32; ++it) {
                    float4 a = xr[it], b = xc[it];
                    sd += (double)a.x * b.x + (double)a.y * b.y +
                          (double)a.z * b.z + (double)a.w * b.w;
                }
                double cs = sd / (na[i] * na[j]);
                keep[e] = (cs >= PT_THR) ? 1.0f : 0.0f;
            }
        }
    }
    __syncthreads();

    int cnt = s_cnt < 256 ? s_cnt : 256;
    int lane = tid & 31;
    int grp = tid >> 5;
    for (int it = grp; it < cnt; it += 8) {
        int ee = s_list[it];
        int row = ei[ee], col = ei[E + ee];
        const float4 a = *(const float4*)(xn + (size_t)row * D_DIM + lane * 4);
        const float4 b = *(const float4*)(xn + (size_t)col * D_DIM + lane * 4);
        double d = (double)a.x * b.x + (double)a.y * b.y +
                   (double)a.z * b.z + (double)a.w * b.w;
        for (int m = 16; m; m >>= 1) d += __shfl_xor(d, m, 32);
        if (lane == 0) {
            double cs = d / (na[row] * na[col]);
            keep[ee] = (cs >= PT_THR) ? 1.0f : 0.0f;
        }
    }
}

// ================= fallback path (small ws): bf16 pipeline, exact prune ====
__global__ void node_pre_bf16(const float* __restrict__ x,
                              const float* __restrict__ ps,
                              const float* __restrict__ pd,
                              const float* __restrict__ po,
                              u16* __restrict__ xnorm,
                              double* __restrict__ cd,
                              int* __restrict__ flags, int N) {
    int g = threadIdx.x >> 5;
    int lane = threadIdx.x & 31;
    int n = blockIdx.x * 8 + g;
    if (n < N) {
        int off = lane * 4;
        const float4 v = *(const float4*)(x + (size_t)n * D_DIM + off);
        float sq = v.x * v.x + v.y * v.y + v.z * v.z + v.w * v.w;
        for (int m = 16; m; m >>= 1) sq += __shfl_xor(sq, m, 32);
        float inv = 1.0f / sqrtf(sq);
        *(ushort4*)(xnorm + (size_t)n * D_DIM + off) =
            make_ushort4(f2bf(v.x * inv), f2bf(v.y * inv), f2bf(v.z * inv), f2bf(v.w * inv));
        if (lane == 0) cd[n] = 0.0;
    }
    if (blockIdx.x == 0 && threadIdx.x < 64) {
        int t = threadIdx.x;
        unsigned long long zs = __ballot(ps[t] == 0.0f || ps[t + 64] == 0.0f);
        unsigned long long zd = __ballot(pd[t] == 0.0f || pd[t + 64] == 0.0f);
        unsigned long long zo = __ballot(po[t] == 0.0f || po[t + 64] == 0.0f);
        if (t == 0) {
            flags[0] = (zs == 0ull);
            flags[1] = (zd == 0ull);
            flags[2] = (zo == 0ull);
        }
    }
}

__global__ void edge_sim_bf16(const u16* __restrict__ xnorm,
                              const int* __restrict__ ei,
                              double* __restrict__ cd, int E) {
    int lane = threadIdx.x & 31;
    int grp = blockIdx.x * 8 + (threadIdx.x >> 5);
    int base = grp * 4;
    if (base >= E) return;
    int r[4], c4[4];
    #pragma unroll
    for (int k = 0; k < 4; ++k) {
        int e = base + k;
        int src = (e < E) ? e : base;
        r[k] = ei[src];
        c4[k] = ei[E + src];
    }
    float d[4];
    #pragma unroll
    for (int k = 0; k < 4; ++k) {
        ushort4 a = *(const ushort4*)(xnorm + (size_t)r[k] * D_DIM + lane * 4);
        ushort4 b = *(const ushort4*)(xnorm + (size_t)c4[k] * D_DIM + lane * 4);
        d[k] = bf2f(a.x) * bf2f(b.x) + bf2f(a.y) * bf2f(b.y) +
               bf2f(a.z) * bf2f(b.z) + bf2f(a.w) * bf2f(b.w);
    }
    for (int m = 16; m; m >>= 1) {
        #pragma unroll
        for (int k = 0; k < 4; ++k) d[k] += __shfl_xor(d[k], m, 32);
    }
    if (lane < 4) {
        int e = base + lane;
        if (e < E) {
            float dv = (lane == 0) ? d[0] : (lane == 1) ? d[1]
                     : (lane == 2) ? d[2] : d[3];
            atomicAdd(&cd[c4[lane]], (double)dv + PK);
        }
    }
}

__global__ void node_prompt_fb(const float* __restrict__ x,
                               const double* __restrict__ cd,
                               const float* __restrict__ ps,
                               const float* __restrict__ pd,
                               const float* __restrict__ po,
                               const int* __restrict__ flags,
                               float* __restrict__ xn,
                               double* __restrict__ na, int N) {
    int g = threadIdx.x >> 5;
    int lane = threadIdx.x & 31;
    int n = blockIdx.x * 8 + g;
    if (n >= N) return;
    double v = cd[n];
    double degd = floor(v * (1.0 / PK) + 0.5);
    float dg = (float)degd;
    float cc = (float)(v - degd * PK);
    float csim = (dg > 0.0f) ? (cc / fmaxf(dg, 1.0f)) : INFINITY;
    bool ms = (csim <= SIM_THR);
    bool md = (dg <= DEG_THR);
    bool mo = !(ms || md);
    int plen = (ms && flags[0]) + (md && flags[1]) + (mo && flags[2]);
    float invp = (plen > 0) ? (1.0f / (float)plen) : 0.0f;
    int off = lane * 4;
    const float4 xv = *(const float4*)(x + (size_t)n * D_DIM + off);
    const float4 s  = *(const float4*)(ps + off);
    const float4 dd = *(const float4*)(pd + off);
    const float4 o  = *(const float4*)(po + off);
    float4 r;
    r.x = xv.x + ((ms ? s.x : 0.0f) + (md ? dd.x : 0.0f) + (mo ? o.x : 0.0f)) * invp;
    r.y = xv.y + ((ms ? s.y : 0.0f) + (md ? dd.y : 0.0f) + (mo ? o.y : 0.0f)) * invp;
    r.z = xv.z + ((ms ? s.z : 0.0f) + (md ? dd.z : 0.0f) + (mo ? o.z : 0.0f)) * invp;
    r.w = xv.w + ((ms ? s.w : 0.0f) + (md ? dd.w : 0.0f) + (mo ? o.w : 0.0f)) * invp;
    *(float4*)(xn + (size_t)n * D_DIM + off) = r;
    double sq = (double)r.x * r.x + (double)r.y * r.y + (double)r.z * r.z + (double)r.w * r.w;
    for (int m = 16; m; m >>= 1) sq += __shfl_xor(sq, m, 32);
    if (lane == 0) {
        double nrm = sqrt(sq);
        na[n] = (nrm > EPS_CS) ? nrm : EPS_CS;
    }
}

__global__ void edge_prune_exact(const float* __restrict__ xn,
                                 const int* __restrict__ ei,
                                 const double* __restrict__ na,
                                 float* __restrict__ keep, int E) {
    int lane = threadIdx.x & 31;
    int grp = blockIdx.x * 8 + (threadIdx.x >> 5);
    int e0 = grp * 2, e1 = e0 + 1;
    if (e0 >= E) return;
    bool has1 = (e1 < E);
    int row0 = ei[e0], col0 = ei[E + e0];
    int row1 = has1 ? ei[e1] : row0;
    int col1 = has1 ? ei[E + e1] : col0;
    const float4 a0 = *(const float4*)(xn + (size_t)row0 * D_DIM + lane * 4);
    const float4 b0 = *(const float4*)(xn + (size_t)col0 * D_DIM + lane * 4);
    const float4 a1 = *(const float4*)(xn + (size_t)row1 * D_DIM + lane * 4);
    const float4 b1 = *(const float4*)(xn + (size_t)col1 * D_DIM + lane * 4);
    double d0 = (double)a0.x * b0.x + (double)a0.y * b0.y +
                (double)a0.z * b0.z + (double)a0.w * b0.w;
    double d1 = (double)a1.x * b1.x + (double)a1.y * b1.y +
                (double)a1.z * b1.z + (double)a1.w * b1.w;
    for (int m = 16; m; m >>= 1) {
        d0 += __shfl_xor(d0, m, 32);
        d1 += __shfl_xor(d1, m, 32);
    }
    if (lane == 0) {
        keep[e0] = ((d0 / (na[row0] * na[col0])) >= PT_THR) ? 1.0f : 0.0f;
    } else if (lane == 1 && has1) {
        keep[e1] = ((d1 / (na[row1] * na[col1])) >= PT_THR) ? 1.0f : 0.0f;
    }
}

extern "C" void kernel_launch(void* const* d_in, const int* in_sizes, int n_in,
                              void* d_out, int out_size, void* d_ws, size_t ws_size,
                              hipStream_t stream) {
    const float* x  = (const float*)d_in[0];
    const int*   ei = (const int*)d_in[1];
    const float* ps = (const float*)d_in[2];
    const float* pd = (const float*)d_in[3];
    const float* po = (const float*)d_in[4];

    const int N = in_sizes[0] / D_DIM;    // 100000
    const int E = in_sizes[1] / 2;        // 640000

    float* xn   = (float*)d_out;                       // [N, D]
    float* keep = (float*)d_out + (size_t)N * D_DIM;   // [E]

    char* ws = (char*)d_ws;
    const int nodeBlocks = (N + 7) / 8;
    const int nbmw = (N + 31) / 32;

    if (ws_size >= (size_t)WS_NEED) {
        double* cd     = (double*)(ws + 0);
        double* na     = (double*)(ws + 800000);
        float* nx      = (float*)(ws + 1600000);
        float* rs      = (float*)(ws + 2000000);
        float* rd      = (float*)(ws + 2400000);
        float* ro      = (float*)(ws + 2800000);
        float* sc      = (float*)(ws + 3200000);
        float* e_arr   = (float*)(ws + 3600000);
        float* pack    = (float*)(ws + 6160000);
        float* cfix    = (float*)(ws + 9360000);
        u32*   bitmap  = (u32*)(ws + 9760000);
        int*   flags   = (int*)(ws + 9772800);
        float* G       = (float*)(ws + 9772816);
        int*   flagcnt = (int*)(ws + 9772852);
        u32*   x8d     = (u32*)d_out;   // int8 table [N,32 dwords], dead before xn write

        node_pre_i8<<<nodeBlocks, 256, 0, stream>>>(x, ps, pd, po, x8d, nx, rs, rd, ro,
                                                    sc, cd, bitmap, nbmw, flags, G,
                                                    flagcnt, N);
        edge_sim_i8<<<(E + 63) / 64, 256, 0, stream>>>(x8d, ei, sc, cd, e_arr, E);
        node_prompt_kernel<<<nodeBlocks, 256, 0, stream>>>(x, cd, ps, pd, po, flags,
                                                           nx, rs, rd, ro,
                                                           xn, na, pack, bitmap, cfix,
                                                           flagcnt, N);
        edge_fix_scan<<<(E + 255) / 256, 256, 0, stream>>>(x, ei, nx, bitmap, flagcnt,
                                                           cfix, E);
        node_fix_kernel<<<nodeBlocks, 256, 0, stream>>>(x, cd, cfix, bitmap, flagcnt,
                                                        ps, pd, po, flags, nx, rs, rd, ro,
                                                        xn, na, pack, N);
        edge_prune_fused<<<(E + 255) / 256, 256, 0, stream>>>(ei, e_arr, pack, G,
                                                              xn, na, keep, E);
    } else {
        // fallback: proven bf16 pipeline, exact prune (needs ~1.6 MB ws)
        double* cd    = (double*)(ws + 0);
        double* na    = (double*)(ws + 800000);
        int*    flags = (int*)(ws + 1600000);
        u16*    xnorm = (u16*)d_out;

        node_pre_bf16<<<nodeBlocks, 256, 0, stream>>>(x, ps, pd, po, xnorm, cd, flags, N);
        edge_sim_bf16<<<(E + 31) / 32, 256, 0, stream>>>(xnorm, ei, cd, E);
        node_prompt_fb<<<nodeBlocks, 256, 0, stream>>>(x, cd, ps, pd, po, flags, xn, na, N);
        edge_prune_exact<<<(E + 15) / 16, 256, 0, stream>>>(xn, ei, na, keep, E);
    }
}

// Round 11
// 103.313 us; speedup vs baseline: 1.1186x; 1.0413x over previous
//
#include <hip/hip_runtime.h>
#include <hip/hip_bf16.h>
#include <math.h>

#define D_DIM 128
#define SIM_THR 0.2f
#define DEG_THR 3.0f
#define PT_THR 0.1
#define EPS_CS 1e-8
#define MARGIN 4e-3f
#define PK 4294967296.0   // 2^32: deg-count scale inside packed f64 atomic

typedef unsigned short u16;
typedef unsigned int u32;

// ---------------- primary ws layout (bytes) ----------------
// 0        cd      double[N]   800000   (zeroed by node_pre)
// 800000   na      double[N]   800000
// 1600000  nx      f32[N]      400000   (|x| per node)
// 2000000  r_s     f32[N]      400000
// 2400000  r_d     f32[N]      400000
// 2800000  r_o     f32[N]      400000
// 3200000  e_arr   f32[E]      2560000
// 5760000  pack    f32[8N]     3200000  {r_s,r_d,r_o,|x|, as,ad,ao,inv_na}
// 8960000  flags   int[4]
// 8960016  G       f32[9]
#define WS_NEED 8960064

__device__ __forceinline__ float bf2f(u16 u) {
    return __uint_as_float(((u32)u) << 16);
}
__device__ __forceinline__ float bflo(u32 w) {
    return __uint_as_float(w << 16);
}
__device__ __forceinline__ float bfhi(u32 w) {
    return __uint_as_float(w & 0xffff0000u);
}

// ---- K1: per node: xnorm bf16, |x|, r_k = dot(x,p_k); zero cd; block 0
//      wave 0 additionally computes prompt flags + 3x3 Gram ----
__global__ void node_pre_kernel(const float* __restrict__ x,
                                const float* __restrict__ ps,
                                const float* __restrict__ pd,
                                const float* __restrict__ po,
                                u16* __restrict__ xnorm,
                                float* __restrict__ nx,
                                float* __restrict__ rs,
                                float* __restrict__ rd,
                                float* __restrict__ ro,
                                double* __restrict__ cd,
                                int* __restrict__ flags,
                                float* __restrict__ G, int N) {
    int g = threadIdx.x >> 5;
    int lane = threadIdx.x & 31;
    int n = blockIdx.x * 8 + g;
    if (n < N) {
        int off = lane * 4;
        const float4 v = *(const float4*)(x + (size_t)n * D_DIM + off);
        const float4 s = *(const float4*)(ps + off);
        const float4 d = *(const float4*)(pd + off);
        const float4 o = *(const float4*)(po + off);
        float sq = v.x * v.x + v.y * v.y + v.z * v.z + v.w * v.w;
        float drs = v.x * s.x + v.y * s.y + v.z * s.z + v.w * s.w;
        float drd = v.x * d.x + v.y * d.y + v.z * d.z + v.w * d.w;
        float dro = v.x * o.x + v.y * o.y + v.z * o.z + v.w * o.w;
        for (int m = 16; m; m >>= 1) {
            sq += __shfl_xor(sq, m, 32);
            drs += __shfl_xor(drs, m, 32);
            drd += __shfl_xor(drd, m, 32);
            dro += __shfl_xor(dro, m, 32);
        }
        float nrm = sqrtf(sq);
        float inv = 1.0f / nrm;
        __hip_bfloat16 ob[4];
        ob[0] = __float2bfloat16(v.x * inv);
        ob[1] = __float2bfloat16(v.y * inv);
        ob[2] = __float2bfloat16(v.z * inv);
        ob[3] = __float2bfloat16(v.w * inv);
        *(ushort4*)(xnorm + (size_t)n * D_DIM + off) =
            make_ushort4(*(u16*)&ob[0], *(u16*)&ob[1], *(u16*)&ob[2], *(u16*)&ob[3]);
        if (lane == 0) {
            nx[n] = nrm;
            rs[n] = drs;
            rd[n] = drd;
            ro[n] = dro;
            cd[n] = 0.0;
        }
    }
    // prompt flags + Gram: one wave of block 0
    if (blockIdx.x == 0 && threadIdx.x < 64) {
        int t = threadIdx.x;
        float s0 = ps[t], s1 = ps[t + 64];
        float d0 = pd[t], d1 = pd[t + 64];
        float o0 = po[t], o1 = po[t + 64];
        float ss = s0 * s0 + s1 * s1;
        float sd = s0 * d0 + s1 * d1;
        float so = s0 * o0 + s1 * o1;
        float dd = d0 * d0 + d1 * d1;
        float dO = d0 * o0 + d1 * o1;
        float oo = o0 * o0 + o1 * o1;
        for (int m = 32; m; m >>= 1) {
            ss += __shfl_xor(ss, m);
            sd += __shfl_xor(sd, m);
            so += __shfl_xor(so, m);
            dd += __shfl_xor(dd, m);
            dO += __shfl_xor(dO, m);
            oo += __shfl_xor(oo, m);
        }
        unsigned long long zs = __ballot(s0 == 0.0f || s1 == 0.0f);
        unsigned long long zd = __ballot(d0 == 0.0f || d1 == 0.0f);
        unsigned long long zo = __ballot(o0 == 0.0f || o1 == 0.0f);
        if (t == 0) {
            flags[0] = (zs == 0ull);
            flags[1] = (zd == 0ull);
            flags[2] = (zo == 0ull);
            G[0] = ss; G[1] = sd; G[2] = so;
            G[3] = sd; G[4] = dd; G[5] = dO;
            G[6] = so; G[7] = dO; G[8] = oo;
        }
    }
}

// ---- K2: bf16 edge sim; 16 lanes/row at 16B/lane (dwordx4 sweet spot),
//      8 edges per 32-lane group (4 per 16-lane half); packed f64 atomic ----
__global__ void edge_sim_kernel(const u16* __restrict__ xnorm,
                                const int* __restrict__ ei,
                                double* __restrict__ cd,
                                float* __restrict__ e_arr,
                                int E) {
    int lane = threadIdx.x & 31;
    int half = lane >> 4;       // which 4-edge batch of this group
    int sub  = lane & 15;       // slice position within the row (16 x 16B)
    int grp = blockIdx.x * 8 + (threadIdx.x >> 5);
    int base = grp * 8;
    if (base >= E) return;
    int eb = base + half * 4;

    int r[4], c4[4];
    #pragma unroll
    for (int k = 0; k < 4; ++k) {
        int e = eb + k;
        int src = (e < E) ? e : base;
        r[k] = ei[src];
        c4[k] = ei[E + src];
    }

    uint4 a[4], b[4];
    #pragma unroll
    for (int k = 0; k < 4; ++k) {
        a[k] = *(const uint4*)(xnorm + (size_t)r[k] * D_DIM + sub * 8);
        b[k] = *(const uint4*)(xnorm + (size_t)c4[k] * D_DIM + sub * 8);
    }

    float d[4];
    #pragma unroll
    for (int k = 0; k < 4; ++k) {
        d[k] = bflo(a[k].x) * bflo(b[k].x) + bfhi(a[k].x) * bfhi(b[k].x) +
               bflo(a[k].y) * bflo(b[k].y) + bfhi(a[k].y) * bfhi(b[k].y) +
               bflo(a[k].z) * bflo(b[k].z) + bfhi(a[k].z) * bfhi(b[k].z) +
               bflo(a[k].w) * bflo(b[k].w) + bfhi(a[k].w) * bfhi(b[k].w);
    }
    // butterfly within the 16-lane half (masks 1,2,4,8 stay inside it)
    #pragma unroll
    for (int m = 8; m; m >>= 1) {
        #pragma unroll
        for (int k = 0; k < 4; ++k) d[k] += __shfl_xor(d[k], m, 32);
    }

    if (sub < 4) {
        int e = eb + sub;
        if (e < E) {
            float dv = (sub == 0) ? d[0] : (sub == 1) ? d[1]
                     : (sub == 2) ? d[2] : d[3];
            int cc = (sub == 0) ? c4[0] : (sub == 1) ? c4[1]
                   : (sub == 2) ? c4[2] : c4[3];
            if (e_arr) e_arr[e] = dv;
            atomicAdd(&cd[cc], (double)dv + PK);
        }
    }
}

// ---- K3: masks -> x_new; na; packed per-node struct for factored prune ----
__global__ void node_prompt_kernel(const float* __restrict__ x,
                                   const double* __restrict__ cd,
                                   const float* __restrict__ ps,
                                   const float* __restrict__ pd,
                                   const float* __restrict__ po,
                                   const int* __restrict__ flags,
                                   const float* __restrict__ nx,
                                   const float* __restrict__ rs,
                                   const float* __restrict__ rd,
                                   const float* __restrict__ ro,
                                   float* __restrict__ xn,
                                   double* __restrict__ na,
                                   float* __restrict__ pack, int N) {
    int g = threadIdx.x >> 5;
    int lane = threadIdx.x & 31;
    int n = blockIdx.x * 8 + g;
    if (n >= N) return;
    double v = cd[n];
    double degd = floor(v * (1.0 / PK) + 0.5);
    float dg = (float)degd;
    float cc = (float)(v - degd * PK);
    float csim = (dg > 0.0f) ? (cc / fmaxf(dg, 1.0f)) : INFINITY;
    bool ms = (csim <= SIM_THR);
    bool md = (dg <= DEG_THR);
    bool mo = !(ms || md);
    int plen = (ms && flags[0]) + (md && flags[1]) + (mo && flags[2]);
    float invp = (plen > 0) ? (1.0f / (float)plen) : 0.0f;

    int off = lane * 4;
    const float4 xv = *(const float4*)(x + (size_t)n * D_DIM + off);
    const float4 s  = *(const float4*)(ps + off);
    const float4 dd = *(const float4*)(pd + off);
    const float4 o  = *(const float4*)(po + off);

    float4 f;
    f.x = (ms ? s.x : 0.0f) + (md ? dd.x : 0.0f) + (mo ? o.x : 0.0f);
    f.y = (ms ? s.y : 0.0f) + (md ? dd.y : 0.0f) + (mo ? o.y : 0.0f);
    f.z = (ms ? s.z : 0.0f) + (md ? dd.z : 0.0f) + (mo ? o.z : 0.0f);
    f.w = (ms ? s.w : 0.0f) + (md ? dd.w : 0.0f) + (mo ? o.w : 0.0f);

    float4 r;
    r.x = xv.x + f.x * invp;
    r.y = xv.y + f.y * invp;
    r.z = xv.z + f.z * invp;
    r.w = xv.w + f.w * invp;

    *(float4*)(xn + (size_t)n * D_DIM + off) = r;

    double sq = (double)r.x * r.x + (double)r.y * r.y + (double)r.z * r.z + (double)r.w * r.w;
    for (int m = 16; m; m >>= 1) sq += __shfl_xor(sq, m, 32);
    if (lane == 0) {
        double nrm = sqrt(sq);
        double nad = (nrm > EPS_CS) ? nrm : EPS_CS;
        na[n] = nad;
        if (pack) {
            float as = ms ? invp : 0.0f;
            float ad = md ? invp : 0.0f;
            float ao = mo ? invp : 0.0f;
            float4 w0 = make_float4(rs[n], rd[n], ro[n], nx[n]);
            float4 w1 = make_float4(as, ad, ao, (float)(1.0 / nad));
            *(float4*)(pack + (size_t)n * 8)     = w0;
            *(float4*)(pack + (size_t)n * 8 + 4) = w1;
        }
    }
}

// ---- K4: fused factored prune + in-block exact fixup (overflow-safe) ----
__global__ void edge_prune_fused(const int* __restrict__ ei,
                                 const float* __restrict__ e_arr,
                                 const float* __restrict__ pack,
                                 const float* __restrict__ G,
                                 const float* __restrict__ xn,
                                 const double* __restrict__ na,
                                 float* __restrict__ keep, int E) {
    __shared__ int s_list[256];
    __shared__ int s_cnt;
    int tid = threadIdx.x;
    if (tid == 0) s_cnt = 0;
    __syncthreads();

    int e = blockIdx.x * 256 + tid;
    if (e < E) {
        int i = ei[e], j = ei[E + e];
        const float4 ri = *(const float4*)(pack + (size_t)i * 8);      // r_s,r_d,r_o,|x|
        const float4 ai = *(const float4*)(pack + (size_t)i * 8 + 4);  // as,ad,ao,inv_na
        const float4 rj = *(const float4*)(pack + (size_t)j * 8);
        const float4 aj = *(const float4*)(pack + (size_t)j * 8 + 4);
        float ev = e_arr[e];
        float dot = ev * ri.w * rj.w
                  + aj.x * ri.x + aj.y * ri.y + aj.z * ri.z
                  + ai.x * rj.x + ai.y * rj.y + ai.z * rj.z;
        dot += ai.x * (G[0] * aj.x + G[1] * aj.y + G[2] * aj.z)
             + ai.y * (G[3] * aj.x + G[4] * aj.y + G[5] * aj.z)
             + ai.z * (G[6] * aj.x + G[7] * aj.y + G[8] * aj.z);
        float cosv = dot * ai.w * aj.w;
        keep[e] = (cosv >= 0.1f) ? 1.0f : 0.0f;
        if (fabsf(cosv - 0.1f) < MARGIN) {
            int idx = atomicAdd(&s_cnt, 1);   // LDS atomic, block-local
            if (idx < 256) {
                s_list[idx] = e;
            } else {
                // overflow: self-service exact recompute (rare)
                const float4* xr = (const float4*)(xn + (size_t)i * D_DIM);
                const float4* xc = (const float4*)(xn + (size_t)j * D_DIM);
                double sd = 0.0;
                for (int it = 0; it < 32; ++it) {
                    float4 a = xr[it], b = xc[it];
                    sd += (double)a.x * b.x + (double)a.y * b.y +
                          (double)a.z * b.z + (double)a.w * b.w;
                }
                double cs = sd / (na[i] * na[j]);
                keep[e] = (cs >= PT_THR) ? 1.0f : 0.0f;
            }
        }
    }
    __syncthreads();

    int cnt = s_cnt < 256 ? s_cnt : 256;
    int lane = tid & 31;
    int grp = tid >> 5;  // 8 groups of 32 lanes
    for (int it = grp; it < cnt; it += 8) {
        int ee = s_list[it];
        int row = ei[ee], col = ei[E + ee];
        const float4 a = *(const float4*)(xn + (size_t)row * D_DIM + lane * 4);
        const float4 b = *(const float4*)(xn + (size_t)col * D_DIM + lane * 4);
        double d = (double)a.x * b.x + (double)a.y * b.y +
                   (double)a.z * b.z + (double)a.w * b.w;
        for (int m = 16; m; m >>= 1) d += __shfl_xor(d, m, 32);
        if (lane == 0) {
            double cs = d / (na[row] * na[col]);
            keep[ee] = (cs >= PT_THR) ? 1.0f : 0.0f;
        }
    }
}

// ---- fallback (R1-proven): full f32/f64 prune over all edges ----
__global__ void edge_prune_kernel(const float* __restrict__ xn,
                                  const int* __restrict__ ei,
                                  const double* __restrict__ na,
                                  float* __restrict__ keep, int E) {
    int lane = threadIdx.x & 31;
    int grp = blockIdx.x * 8 + (threadIdx.x >> 5);
    int e0 = grp * 2, e1 = e0 + 1;
    if (e0 >= E) return;
    bool has1 = (e1 < E);
    int row0 = ei[e0], col0 = ei[E + e0];
    int row1 = has1 ? ei[e1] : row0;
    int col1 = has1 ? ei[E + e1] : col0;

    const float4 a0 = *(const float4*)(xn + (size_t)row0 * D_DIM + lane * 4);
    const float4 b0 = *(const float4*)(xn + (size_t)col0 * D_DIM + lane * 4);
    const float4 a1 = *(const float4*)(xn + (size_t)row1 * D_DIM + lane * 4);
    const float4 b1 = *(const float4*)(xn + (size_t)col1 * D_DIM + lane * 4);

    double d0 = (double)a0.x * b0.x + (double)a0.y * b0.y +
                (double)a0.z * b0.z + (double)a0.w * b0.w;
    double d1 = (double)a1.x * b1.x + (double)a1.y * b1.y +
                (double)a1.z * b1.z + (double)a1.w * b1.w;
    for (int m = 16; m; m >>= 1) {
        d0 += __shfl_xor(d0, m, 32);
        d1 += __shfl_xor(d1, m, 32);
    }
    if (lane == 0) {
        double cs = d0 / (na[row0] * na[col0]);
        keep[e0] = (cs >= PT_THR) ? 1.0f : 0.0f;
    } else if (lane == 1 && has1) {
        double cs = d1 / (na[row1] * na[col1]);
        keep[e1] = (cs >= PT_THR) ? 1.0f : 0.0f;
    }
}

extern "C" void kernel_launch(void* const* d_in, const int* in_sizes, int n_in,
                              void* d_out, int out_size, void* d_ws, size_t ws_size,
                              hipStream_t stream) {
    const float* x  = (const float*)d_in[0];
    const int*   ei = (const int*)d_in[1];
    const float* ps = (const float*)d_in[2];
    const float* pd = (const float*)d_in[3];
    const float* po = (const float*)d_in[4];

    const int N = in_sizes[0] / D_DIM;    // 100000
    const int E = in_sizes[1] / 2;        // 640000

    float* xn    = (float*)d_out;                       // [N, D]
    float* keep  = (float*)d_out + (size_t)N * D_DIM;   // [E]
    u16*   xnorm = (u16*)d_out;                         // bf16 temp, consumed pre-K3

    char* ws = (char*)d_ws;
    const int nodeBlocks = (N + 7) / 8;
    const int simBlocks  = (E + 63) / 64;   // 8 groups x 8 edges per block

    if (ws_size >= (size_t)WS_NEED) {
        double* cd    = (double*)(ws + 0);
        double* na    = (double*)(ws + 800000);
        float* nx     = (float*)(ws + 1600000);
        float* rs     = (float*)(ws + 2000000);
        float* rd     = (float*)(ws + 2400000);
        float* ro     = (float*)(ws + 2800000);
        float* e_arr  = (float*)(ws + 3200000);
        float* pack   = (float*)(ws + 5760000);
        int*   flags  = (int*)(ws + 8960000);
        float* G      = (float*)(ws + 8960016);

        node_pre_kernel<<<nodeBlocks, 256, 0, stream>>>(x, ps, pd, po, xnorm,
                                                        nx, rs, rd, ro, cd, flags, G, N);
        edge_sim_kernel<<<simBlocks, 256, 0, stream>>>(xnorm, ei, cd, e_arr, E);
        node_prompt_kernel<<<nodeBlocks, 256, 0, stream>>>(x, cd, ps, pd, po,
                                                           flags, nx, rs, rd, ro,
                                                           xn, na, pack, N);
        edge_prune_fused<<<(E + 255) / 256, 256, 0, stream>>>(ei, e_arr, pack, G,
                                                              xn, na, keep, E);
    } else {
        // fallback: same pipeline minus factored prune
        double* cd    = (double*)(ws + 0);
        double* na    = (double*)(ws + 800000);
        int*   flags  = (int*)(ws + 1600000);
        float* G      = (float*)(ws + 1600016);
        float* scratch = (float*)(ws + 1600064);

        node_pre_kernel<<<nodeBlocks, 256, 0, stream>>>(x, ps, pd, po, xnorm,
                                                        scratch, scratch, scratch, scratch,
                                                        cd, flags, G, N);
        edge_sim_kernel<<<simBlocks, 256, 0, stream>>>(xnorm, ei, cd, nullptr, E);
        node_prompt_kernel<<<nodeBlocks, 256, 0, stream>>>(x, cd, ps, pd, po,
                                                           flags, nullptr, nullptr, nullptr, nullptr,
                                                           xn, na, nullptr, N);
        edge_prune_kernel<<<(E + 15) / 16, 256, 0, stream>>>(xn, ei, na, keep, E);
    }
}

// Round 12
// 101.163 us; speedup vs baseline: 1.1424x; 1.0213x over previous
//
#include <hip/hip_runtime.h>
#include <hip/hip_bf16.h>
#include <math.h>

#define D_DIM 128
#define SIM_THR 0.2f
#define DEG_THR 3.0f
#define PT_THR 0.1
#define EPS_CS 1e-8
#define MARGIN 4e-3f
#define PK 4294967296.0   // 2^32: deg-count scale inside packed f64 atomic

typedef unsigned short u16;
typedef unsigned int u32;

// ---------------- primary ws layout (bytes) ----------------
// 0        cd      double[N]   800000   (zeroed by node_pre)
// 800000   na      double[N]   800000
// 1600000  nx      f32[N]      400000   (|x| per node)
// 2000000  r_s     f32[N]      400000
// 2400000  r_d     f32[N]      400000
// 2800000  r_o     f32[N]      400000
// 3200000  e_arr   f32[E]      2560000
// 5760000  pack    f32[8N]     3200000  {r_s,r_d,r_o,|x|, as,ad,ao,inv_na}
// 8960000  flags   int[4]
// 8960016  G       f32[9]
#define WS_NEED 8960064

__device__ __forceinline__ float bf2f(u16 u) {
    return __uint_as_float(((u32)u) << 16);
}

// ---- K1: per node: xnorm bf16, |x|, r_k = dot(x,p_k); zero cd; block 0
//      wave 0 additionally computes prompt flags + 3x3 Gram ----
__global__ void node_pre_kernel(const float* __restrict__ x,
                                const float* __restrict__ ps,
                                const float* __restrict__ pd,
                                const float* __restrict__ po,
                                u16* __restrict__ xnorm,
                                float* __restrict__ nx,
                                float* __restrict__ rs,
                                float* __restrict__ rd,
                                float* __restrict__ ro,
                                double* __restrict__ cd,
                                int* __restrict__ flags,
                                float* __restrict__ G, int N) {
    int g = threadIdx.x >> 5;
    int lane = threadIdx.x & 31;
    int n = blockIdx.x * 8 + g;
    if (n < N) {
        int off = lane * 4;
        const float4 v = *(const float4*)(x + (size_t)n * D_DIM + off);
        const float4 s = *(const float4*)(ps + off);
        const float4 d = *(const float4*)(pd + off);
        const float4 o = *(const float4*)(po + off);
        float sq = v.x * v.x + v.y * v.y + v.z * v.z + v.w * v.w;
        float drs = v.x * s.x + v.y * s.y + v.z * s.z + v.w * s.w;
        float drd = v.x * d.x + v.y * d.y + v.z * d.z + v.w * d.w;
        float dro = v.x * o.x + v.y * o.y + v.z * o.z + v.w * o.w;
        for (int m = 16; m; m >>= 1) {
            sq += __shfl_xor(sq, m, 32);
            drs += __shfl_xor(drs, m, 32);
            drd += __shfl_xor(drd, m, 32);
            dro += __shfl_xor(dro, m, 32);
        }
        float nrm = sqrtf(sq);
        float inv = 1.0f / nrm;
        __hip_bfloat16 ob[4];
        ob[0] = __float2bfloat16(v.x * inv);
        ob[1] = __float2bfloat16(v.y * inv);
        ob[2] = __float2bfloat16(v.z * inv);
        ob[3] = __float2bfloat16(v.w * inv);
        *(ushort4*)(xnorm + (size_t)n * D_DIM + off) =
            make_ushort4(*(u16*)&ob[0], *(u16*)&ob[1], *(u16*)&ob[2], *(u16*)&ob[3]);
        if (lane == 0) {
            nx[n] = nrm;
            rs[n] = drs;
            rd[n] = drd;
            ro[n] = dro;
            cd[n] = 0.0;
        }
    }
    // prompt flags + Gram: one wave of block 0
    if (blockIdx.x == 0 && threadIdx.x < 64) {
        int t = threadIdx.x;
        float s0 = ps[t], s1 = ps[t + 64];
        float d0 = pd[t], d1 = pd[t + 64];
        float o0 = po[t], o1 = po[t + 64];
        float ss = s0 * s0 + s1 * s1;
        float sd = s0 * d0 + s1 * d1;
        float so = s0 * o0 + s1 * o1;
        float dd = d0 * d0 + d1 * d1;
        float dO = d0 * o0 + d1 * o1;
        float oo = o0 * o0 + o1 * o1;
        for (int m = 32; m; m >>= 1) {
            ss += __shfl_xor(ss, m);
            sd += __shfl_xor(sd, m);
            so += __shfl_xor(so, m);
            dd += __shfl_xor(dd, m);
            dO += __shfl_xor(dO, m);
            oo += __shfl_xor(oo, m);
        }
        unsigned long long zs = __ballot(s0 == 0.0f || s1 == 0.0f);
        unsigned long long zd = __ballot(d0 == 0.0f || d1 == 0.0f);
        unsigned long long zo = __ballot(o0 == 0.0f || o1 == 0.0f);
        if (t == 0) {
            flags[0] = (zs == 0ull);
            flags[1] = (zd == 0ull);
            flags[2] = (zo == 0ull);
            G[0] = ss; G[1] = sd; G[2] = so;
            G[3] = sd; G[4] = dd; G[5] = dO;
            G[6] = so; G[7] = dO; G[8] = oo;
        }
    }
}

// ---- K2: bf16 edge sim, 4 edges per 32-lane group (best-measured variant:
//      46.5 us, 24 VGPR); one packed f64 atomic per edge ----
__global__ void edge_sim_kernel(const u16* __restrict__ xnorm,
                                const int* __restrict__ ei,
                                double* __restrict__ cd,
                                float* __restrict__ e_arr,
                                int E) {
    int lane = threadIdx.x & 31;
    int grp = blockIdx.x * 8 + (threadIdx.x >> 5);
    int base = grp * 4;
    if (base >= E) return;

    int r[4], c4[4];
    #pragma unroll
    for (int k = 0; k < 4; ++k) {
        int e = base + k;
        int src = (e < E) ? e : base;
        r[k] = ei[src];
        c4[k] = ei[E + src];
    }

    ushort4 a[4], b[4];
    #pragma unroll
    for (int k = 0; k < 4; ++k) {
        a[k] = *(const ushort4*)(xnorm + (size_t)r[k] * D_DIM + lane * 4);
        b[k] = *(const ushort4*)(xnorm + (size_t)c4[k] * D_DIM + lane * 4);
    }

    float d[4];
    #pragma unroll
    for (int k = 0; k < 4; ++k) {
        d[k] = bf2f(a[k].x) * bf2f(b[k].x) + bf2f(a[k].y) * bf2f(b[k].y) +
               bf2f(a[k].z) * bf2f(b[k].z) + bf2f(a[k].w) * bf2f(b[k].w);
    }
    for (int m = 16; m; m >>= 1) {
        #pragma unroll
        for (int k = 0; k < 4; ++k) d[k] += __shfl_xor(d[k], m, 32);
    }

    if (lane < 4) {
        int e = base + lane;
        if (e < E) {
            float dv = (lane == 0) ? d[0] : (lane == 1) ? d[1]
                     : (lane == 2) ? d[2] : d[3];
            if (e_arr) e_arr[e] = dv;
            atomicAdd(&cd[c4[lane]], (double)dv + PK);
        }
    }
}

// ---- K3: masks -> x_new; na; packed per-node struct for factored prune ----
__global__ void node_prompt_kernel(const float* __restrict__ x,
                                   const double* __restrict__ cd,
                                   const float* __restrict__ ps,
                                   const float* __restrict__ pd,
                                   const float* __restrict__ po,
                                   const int* __restrict__ flags,
                                   const float* __restrict__ nx,
                                   const float* __restrict__ rs,
                                   const float* __restrict__ rd,
                                   const float* __restrict__ ro,
                                   float* __restrict__ xn,
                                   double* __restrict__ na,
                                   float* __restrict__ pack, int N) {
    int g = threadIdx.x >> 5;
    int lane = threadIdx.x & 31;
    int n = blockIdx.x * 8 + g;
    if (n >= N) return;
    double v = cd[n];
    double degd = floor(v * (1.0 / PK) + 0.5);
    float dg = (float)degd;
    float cc = (float)(v - degd * PK);
    float csim = (dg > 0.0f) ? (cc / fmaxf(dg, 1.0f)) : INFINITY;
    bool ms = (csim <= SIM_THR);
    bool md = (dg <= DEG_THR);
    bool mo = !(ms || md);
    int plen = (ms && flags[0]) + (md && flags[1]) + (mo && flags[2]);
    float invp = (plen > 0) ? (1.0f / (float)plen) : 0.0f;

    int off = lane * 4;
    const float4 xv = *(const float4*)(x + (size_t)n * D_DIM + off);
    const float4 s  = *(const float4*)(ps + off);
    const float4 dd = *(const float4*)(pd + off);
    const float4 o  = *(const float4*)(po + off);

    float4 f;
    f.x = (ms ? s.x : 0.0f) + (md ? dd.x : 0.0f) + (mo ? o.x : 0.0f);
    f.y = (ms ? s.y : 0.0f) + (md ? dd.y : 0.0f) + (mo ? o.y : 0.0f);
    f.z = (ms ? s.z : 0.0f) + (md ? dd.z : 0.0f) + (mo ? o.z : 0.0f);
    f.w = (ms ? s.w : 0.0f) + (md ? dd.w : 0.0f) + (mo ? o.w : 0.0f);

    float4 r;
    r.x = xv.x + f.x * invp;
    r.y = xv.y + f.y * invp;
    r.z = xv.z + f.z * invp;
    r.w = xv.w + f.w * invp;

    *(float4*)(xn + (size_t)n * D_DIM + off) = r;

    double sq = (double)r.x * r.x + (double)r.y * r.y + (double)r.z * r.z + (double)r.w * r.w;
    for (int m = 16; m; m >>= 1) sq += __shfl_xor(sq, m, 32);
    if (lane == 0) {
        double nrm = sqrt(sq);
        double nad = (nrm > EPS_CS) ? nrm : EPS_CS;
        na[n] = nad;
        if (pack) {
            float as = ms ? invp : 0.0f;
            float ad = md ? invp : 0.0f;
            float ao = mo ? invp : 0.0f;
            float4 w0 = make_float4(rs[n], rd[n], ro[n], nx[n]);
            float4 w1 = make_float4(as, ad, ao, (float)(1.0 / nad));
            *(float4*)(pack + (size_t)n * 8)     = w0;
            *(float4*)(pack + (size_t)n * 8 + 4) = w1;
        }
    }
}

// ---- K4: fused factored prune + in-block exact fixup (overflow-safe) ----
__global__ void edge_prune_fused(const int* __restrict__ ei,
                                 const float* __restrict__ e_arr,
                                 const float* __restrict__ pack,
                                 const float* __restrict__ G,
                                 const float* __restrict__ xn,
                                 const double* __restrict__ na,
                                 float* __restrict__ keep, int E) {
    __shared__ int s_list[256];
    __shared__ int s_cnt;
    int tid = threadIdx.x;
    if (tid == 0) s_cnt = 0;
    __syncthreads();

    int e = blockIdx.x * 256 + tid;
    if (e < E) {
        int i = ei[e], j = ei[E + e];
        const float4 ri = *(const float4*)(pack + (size_t)i * 8);      // r_s,r_d,r_o,|x|
        const float4 ai = *(const float4*)(pack + (size_t)i * 8 + 4);  // as,ad,ao,inv_na
        const float4 rj = *(const float4*)(pack + (size_t)j * 8);
        const float4 aj = *(const float4*)(pack + (size_t)j * 8 + 4);
        float ev = e_arr[e];
        float dot = ev * ri.w * rj.w
                  + aj.x * ri.x + aj.y * ri.y + aj.z * ri.z
                  + ai.x * rj.x + ai.y * rj.y + ai.z * rj.z;
        dot += ai.x * (G[0] * aj.x + G[1] * aj.y + G[2] * aj.z)
             + ai.y * (G[3] * aj.x + G[4] * aj.y + G[5] * aj.z)
             + ai.z * (G[6] * aj.x + G[7] * aj.y + G[8] * aj.z);
        float cosv = dot * ai.w * aj.w;
        keep[e] = (cosv >= 0.1f) ? 1.0f : 0.0f;
        if (fabsf(cosv - 0.1f) < MARGIN) {
            int idx = atomicAdd(&s_cnt, 1);   // LDS atomic, block-local
            if (idx < 256) {
                s_list[idx] = e;
            } else {
                // overflow: self-service exact recompute (rare)
                const float4* xr = (const float4*)(xn + (size_t)i * D_DIM);
                const float4* xc = (const float4*)(xn + (size_t)j * D_DIM);
                double sd = 0.0;
                for (int it = 0; it < 32; ++it) {
                    float4 a = xr[it], b = xc[it];
                    sd += (double)a.x * b.x + (double)a.y * b.y +
                          (double)a.z * b.z + (double)a.w * b.w;
                }
                double cs = sd / (na[i] * na[j]);
                keep[e] = (cs >= PT_THR) ? 1.0f : 0.0f;
            }
        }
    }
    __syncthreads();

    int cnt = s_cnt < 256 ? s_cnt : 256;
    int lane = tid & 31;
    int grp = tid >> 5;  // 8 groups of 32 lanes
    for (int it = grp; it < cnt; it += 8) {
        int ee = s_list[it];
        int row = ei[ee], col = ei[E + ee];
        const float4 a = *(const float4*)(xn + (size_t)row * D_DIM + lane * 4);
        const float4 b = *(const float4*)(xn + (size_t)col * D_DIM + lane * 4);
        double d = (double)a.x * b.x + (double)a.y * b.y +
                   (double)a.z * b.z + (double)a.w * b.w;
        for (int m = 16; m; m >>= 1) d += __shfl_xor(d, m, 32);
        if (lane == 0) {
            double cs = d / (na[row] * na[col]);
            keep[ee] = (cs >= PT_THR) ? 1.0f : 0.0f;
        }
    }
}

// ---- fallback (R1-proven): full f32/f64 prune over all edges ----
__global__ void edge_prune_kernel(const float* __restrict__ xn,
                                  const int* __restrict__ ei,
                                  const double* __restrict__ na,
                                  float* __restrict__ keep, int E) {
    int lane = threadIdx.x & 31;
    int grp = blockIdx.x * 8 + (threadIdx.x >> 5);
    int e0 = grp * 2, e1 = e0 + 1;
    if (e0 >= E) return;
    bool has1 = (e1 < E);
    int row0 = ei[e0], col0 = ei[E + e0];
    int row1 = has1 ? ei[e1] : row0;
    int col1 = has1 ? ei[E + e1] : col0;

    const float4 a0 = *(const float4*)(xn + (size_t)row0 * D_DIM + lane * 4);
    const float4 b0 = *(const float4*)(xn + (size_t)col0 * D_DIM + lane * 4);
    const float4 a1 = *(const float4*)(xn + (size_t)row1 * D_DIM + lane * 4);
    const float4 b1 = *(const float4*)(xn + (size_t)col1 * D_DIM + lane * 4);

    double d0 = (double)a0.x * b0.x + (double)a0.y * b0.y +
                (double)a0.z * b0.z + (double)a0.w * b0.w;
    double d1 = (double)a1.x * b1.x + (double)a1.y * b1.y +
                (double)a1.z * b1.z + (double)a1.w * b1.w;
    for (int m = 16; m; m >>= 1) {
        d0 += __shfl_xor(d0, m, 32);
        d1 += __shfl_xor(d1, m, 32);
    }
    if (lane == 0) {
        double cs = d0 / (na[row0] * na[col0]);
        keep[e0] = (cs >= PT_THR) ? 1.0f : 0.0f;
    } else if (lane == 1 && has1) {
        double cs = d1 / (na[row1] * na[col1]);
        keep[e1] = (cs >= PT_THR) ? 1.0f : 0.0f;
    }
}

extern "C" void kernel_launch(void* const* d_in, const int* in_sizes, int n_in,
                              void* d_out, int out_size, void* d_ws, size_t ws_size,
                              hipStream_t stream) {
    const float* x  = (const float*)d_in[0];
    const int*   ei = (const int*)d_in[1];
    const float* ps = (const float*)d_in[2];
    const float* pd = (const float*)d_in[3];
    const float* po = (const float*)d_in[4];

    const int N = in_sizes[0] / D_DIM;    // 100000
    const int E = in_sizes[1] / 2;        // 640000

    float* xn    = (float*)d_out;                       // [N, D]
    float* keep  = (float*)d_out + (size_t)N * D_DIM;   // [E]
    u16*   xnorm = (u16*)d_out;                         // bf16 temp, consumed pre-K3

    char* ws = (char*)d_ws;
    const int nodeBlocks = (N + 7) / 8;
    const int simBlocks  = (E + 31) / 32;   // 8 groups x 4 edges per block

    if (ws_size >= (size_t)WS_NEED) {
        double* cd    = (double*)(ws + 0);
        double* na    = (double*)(ws + 800000);
        float* nx     = (float*)(ws + 1600000);
        float* rs     = (float*)(ws + 2000000);
        float* rd     = (float*)(ws + 2400000);
        float* ro     = (float*)(ws + 2800000);
        float* e_arr  = (float*)(ws + 3200000);
        float* pack   = (float*)(ws + 5760000);
        int*   flags  = (int*)(ws + 8960000);
        float* G      = (float*)(ws + 8960016);

        node_pre_kernel<<<nodeBlocks, 256, 0, stream>>>(x, ps, pd, po, xnorm,
                                                        nx, rs, rd, ro, cd, flags, G, N);
        edge_sim_kernel<<<simBlocks, 256, 0, stream>>>(xnorm, ei, cd, e_arr, E);
        node_prompt_kernel<<<nodeBlocks, 256, 0, stream>>>(x, cd, ps, pd, po,
                                                           flags, nx, rs, rd, ro,
                                                           xn, na, pack, N);
        edge_prune_fused<<<(E + 255) / 256, 256, 0, stream>>>(ei, e_arr, pack, G,
                                                              xn, na, keep, E);
    } else {
        // fallback: same pipeline minus factored prune
        double* cd    = (double*)(ws + 0);
        double* na    = (double*)(ws + 800000);
        int*   flags  = (int*)(ws + 1600000);
        float* G      = (float*)(ws + 1600016);
        float* scratch = (float*)(ws + 1600064);

        node_pre_kernel<<<nodeBlocks, 256, 0, stream>>>(x, ps, pd, po, xnorm,
                                                        scratch, scratch, scratch, scratch,
                                                        cd, flags, G, N);
        edge_sim_kernel<<<simBlocks, 256, 0, stream>>>(xnorm, ei, cd, nullptr, E);
        node_prompt_kernel<<<nodeBlocks, 256, 0, stream>>>(x, cd, ps, pd, po,
                                                           flags, nullptr, nullptr, nullptr, nullptr,
                                                           xn, na, nullptr, N);
        edge_prune_kernel<<<(E + 15) / 16, 256, 0, stream>>>(xn, ei, na, keep, E);
    }
}